// Round 1
// baseline (304.050 us; speedup 1.0000x reference)
//
#include <hip/hip_runtime.h>
#include <hip/hip_bf16.h>

// ---------------------------------------------------------------------------
// Fused dual-attention block (TCA_309237645935) for gfx950.
//
// Layout insight: reference's .view(H,B,T,dkh) is a row-major reinterpret of
// the flat (4096 x 1024) projection matrix; group g = h*4+b (64 groups) is a
// CONTIGUOUS [1024][64] slice at offset g*65536. Attention outputs in group
// layout are already the (b,t,c) layout. So: everything stays contiguous.
//
// All matmuls: bf16 MFMA 16x16x32, f32 accum.  LDS tiles sub-tiled as
// [2][rows][32] (row stride 64B) => frag ds_read_b128 is ~2-way conflicted
// (free per m136) without swizzle.
// ---------------------------------------------------------------------------

typedef __attribute__((ext_vector_type(8))) short short8;
typedef __attribute__((ext_vector_type(4))) float f32x4;

__device__ __forceinline__ f32x4 mfma16(short8 a, short8 b, f32x4 c) {
  return __builtin_amdgcn_mfma_f32_16x16x32_bf16(a, b, c, 0, 0, 0);
}

__device__ __forceinline__ unsigned short f2b(float f) {
  __hip_bfloat16 h = __float2bfloat16(f);
  return *reinterpret_cast<unsigned short*>(&h);
}

__device__ __forceinline__ void gload_lds16(const void* g, void* l) {
  __builtin_amdgcn_global_load_lds(
      (const __attribute__((address_space(1))) void*)g,
      (__attribute__((address_space(3))) void*)l, 16, 0, 0);
}

// ---------------- cast x (f32 -> bf16), 8 elems/thread ----------------------
__global__ __launch_bounds__(256) void k_cast_x(const float* __restrict__ x,
                                                unsigned short* __restrict__ xb) {
  int i = (blockIdx.x * 256 + threadIdx.x) * 8;
  float4 a = *reinterpret_cast<const float4*>(x + i);
  float4 b = *reinterpret_cast<const float4*>(x + i + 4);
  short8 o;
  o[0] = (short)f2b(a.x); o[1] = (short)f2b(a.y);
  o[2] = (short)f2b(a.z); o[3] = (short)f2b(a.w);
  o[4] = (short)f2b(b.x); o[5] = (short)f2b(b.y);
  o[6] = (short)f2b(b.z); o[7] = (short)f2b(b.w);
  *reinterpret_cast<short8*>(xb + i) = o;
}

// ---------- transpose+cast weights: W[k][n] f32 -> WT[n][k] bf16 ------------
__global__ __launch_bounds__(256) void k_transW(const float* __restrict__ Wq,
                                                const float* __restrict__ Wk,
                                                const float* __restrict__ Wv,
                                                const float* __restrict__ Wo,
                                                unsigned short* __restrict__ WcatT,
                                                unsigned short* __restrict__ WoT) {
  int wsel = blockIdx.z;
  const float* src = wsel == 0 ? Wq : wsel == 1 ? Wk : wsel == 2 ? Wv : Wo;
  unsigned short* dst = (wsel < 3) ? (WcatT + (size_t)wsel * 1024 * 1024) : WoT;
  int k0 = blockIdx.x * 64, n0 = blockIdx.y * 64;
  __shared__ float tile[64][65];
  int tr = threadIdx.x >> 6, tc = threadIdx.x & 63;
#pragma unroll
  for (int i = 0; i < 16; ++i) {
    int r = i * 4 + tr;
    tile[r][tc] = src[(size_t)(k0 + r) * 1024 + n0 + tc];
  }
  __syncthreads();
#pragma unroll
  for (int i = 0; i < 16; ++i) {
    int r = i * 4 + tr;
    dst[(size_t)(n0 + r) * 1024 + k0 + tc] = f2b(tile[tc][r]);
  }
}

// -------- pack adj (bf16, hi 16b) + mask bit (lo bit) into u32 --------------
__global__ __launch_bounds__(256) void k_pack(const float* __restrict__ adj,
                                              const int* __restrict__ mask,
                                              unsigned int* __restrict__ AM) {
  int i = (blockIdx.x * 256 + threadIdx.x) * 4;
  float4 a = *reinterpret_cast<const float4*>(adj + i);
  int4 m = *reinterpret_cast<const int4*>(mask + i);
  uint4 o;
  o.x = ((unsigned)f2b(a.x) << 16) | (m.x != 0 ? 1u : 0u);
  o.y = ((unsigned)f2b(a.y) << 16) | (m.y != 0 ? 1u : 0u);
  o.z = ((unsigned)f2b(a.z) << 16) | (m.z != 0 ? 1u : 0u);
  o.w = ((unsigned)f2b(a.w) << 16) | (m.w != 0 ? 1u : 0u);
  *reinterpret_cast<uint4*>(AM + i) = o;
}

// ---------------- m97-style bf16 GEMM: C = A(MxK) @ BT(NxK)^T + bias --------
// MODE 0: write bf16 into Q/K/V (col 0..1023 -> Q, ... per n>>10), bias b0/1/2
// MODE 1: write f32 into outF, bias b0
template <int MODE>
__global__ __launch_bounds__(256) void k_gemm(
    const unsigned short* __restrict__ A, const unsigned short* __restrict__ BT,
    float* __restrict__ outF,
    unsigned short* __restrict__ oQ, unsigned short* __restrict__ oK,
    unsigned short* __restrict__ oV,
    const float* __restrict__ b0, const float* __restrict__ b1,
    const float* __restrict__ b2, int M, int N, int K) {
  __shared__ unsigned short As[128 * 32], Bs[128 * 32];
  const int tid = threadIdx.x;
  const int w = tid >> 6, l = tid & 63, l15 = l & 15, l4 = l >> 4;
  const int m0 = blockIdx.x * 128, n0 = blockIdx.y * 128;
  const int wm = (w >> 1) * 64, wn = (w & 1) * 64;
  f32x4 acc[4][4];
#pragma unroll
  for (int i = 0; i < 4; ++i)
#pragma unroll
    for (int j = 0; j < 4; ++j) acc[i][j] = f32x4{0.f, 0.f, 0.f, 0.f};

  const int nkt = K >> 5;
  for (int kt = 0; kt < nkt; ++kt) {
#pragma unroll
    for (int i = 0; i < 2; ++i) {
      int c = i * 256 + tid;
      gload_lds16(A + (size_t)(m0 + (c >> 2)) * K + kt * 32 + (c & 3) * 8,
                  (char*)As + c * 16);
      gload_lds16(BT + (size_t)(n0 + (c >> 2)) * K + kt * 32 + (c & 3) * 8,
                  (char*)Bs + c * 16);
    }
    __syncthreads();
    short8 af[4], bf[4];
#pragma unroll
    for (int i = 0; i < 4; ++i)
      af[i] = *reinterpret_cast<const short8*>(As + (wm + i * 16 + l15) * 32 + l4 * 8);
#pragma unroll
    for (int j = 0; j < 4; ++j)
      bf[j] = *reinterpret_cast<const short8*>(Bs + (wn + j * 16 + l15) * 32 + l4 * 8);
#pragma unroll
    for (int i = 0; i < 4; ++i)
#pragma unroll
      for (int j = 0; j < 4; ++j) acc[i][j] = mfma16(af[i], bf[j], acc[i][j]);
    __syncthreads();
  }
  // epilogue: C row = (l>>4)*4+reg, col = l&15  [m89 verified layout]
#pragma unroll
  for (int i = 0; i < 4; ++i)
#pragma unroll
    for (int j = 0; j < 4; ++j) {
      int gr0 = m0 + wm + i * 16 + l4 * 4;
      int gc = n0 + wn + j * 16 + l15;
      if (MODE == 0) {
        int mat = gc >> 10, nl = gc & 1023;
        const float* bp = mat == 0 ? b0 : mat == 1 ? b1 : b2;
        unsigned short* op = mat == 0 ? oQ : mat == 1 ? oK : oV;
        float bb = bp[nl];
#pragma unroll
        for (int r = 0; r < 4; ++r)
          op[(size_t)(gr0 + r) * 1024 + nl] = f2b(acc[i][j][r] + bb);
      } else {
        float bb = b0[gc];
#pragma unroll
        for (int r = 0; r < 4; ++r)
          outF[(size_t)(gr0 + r) * N + gc] = acc[i][j][r] + bb;
      }
    }
}

// ---------------- dual-softmax flash attention ------------------------------
// grid (16 q-tiles, 64 groups), 256 thr (4 waves), each wave: 16 q rows.
// Per K-tile (64 keys): QK^T (8 MFMA/wave), dual online softmax, P->LDS,
// 2 x PV (16 MFMA/wave).
__global__ __launch_bounds__(256) void k_attn(
    const unsigned short* __restrict__ Qb, const unsigned short* __restrict__ Kb,
    const unsigned short* __restrict__ Vb, const unsigned int* __restrict__ AM,
    float* __restrict__ Xg, float* __restrict__ Xl) {
  const int g = blockIdx.y;
  const int q0 = blockIdx.x * 64;
  const int tid = threadIdx.x;
  const int w = tid >> 6, l = tid & 63, l15 = l & 15, l4 = l >> 4;

  __shared__ unsigned short Kt[2][64][32];        // [dk-sub][key][d&31]
  __shared__ unsigned short Vt[2][64][32];        // [ks-sub][d][k&31]
  __shared__ unsigned short Ps[4][2][2][16][32];  // [wave][map][ks][q][k&31]

  const size_t gbase = (size_t)g << 16;
  const unsigned short* Qg = Qb + gbase;
  const unsigned short* Kg = Kb + gbase;
  const unsigned short* Vg = Vb + gbase;

  // Q fragments (A-operand): lane: Q[q0+16w+l15][dk*32 + l4*8 + j]
  short8 qf[2];
  {
    const unsigned short* qp = Qg + (size_t)(q0 + w * 16 + l15) * 64 + l4 * 8;
    qf[0] = *reinterpret_cast<const short8*>(qp);
    qf[1] = *reinterpret_cast<const short8*>(qp + 32);
  }

  f32x4 accg[4], accl[4];
#pragma unroll
  for (int d = 0; d < 4; ++d) {
    accg[d] = f32x4{0.f, 0.f, 0.f, 0.f};
    accl[d] = f32x4{0.f, 0.f, 0.f, 0.f};
  }
  float mg[4], ml[4], lg[4], ll[4];
#pragma unroll
  for (int r = 0; r < 4; ++r) { mg[r] = ml[r] = -1e30f; lg[r] = ll[r] = 0.f; }

  const int qrow = q0 + w * 16 + l4 * 4;  // + r
  const float nf = 0.03125f;              // 1/sqrt(1024)

  for (int kt = 0; kt < 16; ++kt) {
    const int kk0 = kt * 64;
    // stage K sub-tiled: lds chunk c -> ks=c>>8, key=(c>>2)&63, c16=c&3
#pragma unroll
    for (int i = 0; i < 2; ++i) {
      int c = i * 256 + tid;
      int ks = c >> 8, row = (c >> 2) & 63, c16 = c & 3;
      gload_lds16(Kg + (size_t)(kk0 + row) * 64 + ks * 32 + c16 * 8,
                  (char*)Kt + c * 16);
    }
    // stage V transposed (reg path): thread: k=(tid&31)+32i, d0=(tid>>5)*8
#pragma unroll
    for (int i = 0; i < 2; ++i) {
      int k = (tid & 31) + i * 32;
      int d0 = (tid >> 5) * 8;
      short8 v = *reinterpret_cast<const short8*>(Vg + (size_t)(kk0 + k) * 64 + d0);
      int ks = k >> 5, kl = k & 31;
#pragma unroll
      for (int j = 0; j < 8; ++j) Vt[ks][d0 + j][kl] = (unsigned short)v[j];
    }
    __syncthreads();

    // S = Q K^T : B-operand lane: K[kk0+cb*16+l15][dk*32+l4*8+j]
    f32x4 accs[4];
#pragma unroll
    for (int cb = 0; cb < 4; ++cb) accs[cb] = f32x4{0.f, 0.f, 0.f, 0.f};
#pragma unroll
    for (int cb = 0; cb < 4; ++cb)
#pragma unroll
      for (int dk = 0; dk < 2; ++dk)
        accs[cb] = mfma16(qf[dk],
                          *reinterpret_cast<const short8*>(&Kt[dk][cb * 16 + l15][l4 * 8]),
                          accs[cb]);

    // logits + adj + mask
    float gv[4][4];
    int msk[4][4];
#pragma unroll
    for (int cb = 0; cb < 4; ++cb) {
      int kc = kk0 + cb * 16 + l15;
#pragma unroll
      for (int r = 0; r < 4; ++r) {
        unsigned int am = AM[(size_t)(qrow + r) * 1024 + kc];
        union { unsigned int u; float f; } cv; cv.u = am & 0xffff0000u;
        gv[cb][r] = accs[cb][r] * nf + cv.f;
        msk[cb][r] = (int)(am & 1u);
      }
    }
    // row maxes (in-lane over cb, then shfl over the 16-lane k group)
    float rmg[4], rml[4];
#pragma unroll
    for (int r = 0; r < 4; ++r) {
      float a = fmaxf(fmaxf(gv[0][r], gv[1][r]), fmaxf(gv[2][r], gv[3][r]));
      float b = -1e9f;
#pragma unroll
      for (int cb = 0; cb < 4; ++cb) b = fmaxf(b, msk[cb][r] ? gv[cb][r] : -1e9f);
#pragma unroll
      for (int off = 1; off < 16; off <<= 1) {
        a = fmaxf(a, __shfl_xor(a, off));
        b = fmaxf(b, __shfl_xor(b, off));
      }
      rmg[r] = a; rml[r] = b;
    }
    // online rescale
    float sg[4], sl[4];
#pragma unroll
    for (int r = 0; r < 4; ++r) {
      float mng = fmaxf(mg[r], rmg[r]);
      float cg = __expf(mg[r] - mng);
      mg[r] = mng; lg[r] *= cg;
      accg[0][r] *= cg; accg[1][r] *= cg; accg[2][r] *= cg; accg[3][r] *= cg;
      float mnl = fmaxf(ml[r], rml[r]);
      float cl = __expf(ml[r] - mnl);
      ml[r] = mnl; ll[r] *= cl;
      accl[0][r] *= cl; accl[1][r] *= cl; accl[2][r] *= cl; accl[3][r] *= cl;
      sg[r] = 0.f; sl[r] = 0.f;
    }
    // P = exp(S - m), write both maps to LDS (bf16), accumulate row sums
#pragma unroll
    for (int cb = 0; cb < 4; ++cb)
#pragma unroll
      for (int r = 0; r < 4; ++r) {
        float pg = __expf(gv[cb][r] - mg[r]);
        float pl = msk[cb][r] ? __expf(gv[cb][r] - ml[r]) : 0.f;
        sg[r] += pg; sl[r] += pl;
        Ps[w][0][cb >> 1][l4 * 4 + r][(cb & 1) * 16 + l15] = f2b(pg);
        Ps[w][1][cb >> 1][l4 * 4 + r][(cb & 1) * 16 + l15] = f2b(pl);
      }
#pragma unroll
    for (int r = 0; r < 4; ++r) {
      float a = sg[r], b = sl[r];
#pragma unroll
      for (int off = 1; off < 16; off <<= 1) {
        a += __shfl_xor(a, off);
        b += __shfl_xor(b, off);
      }
      lg[r] += a; ll[r] += b;
    }
    // PV: A lane: P[l15][ks*32+l4*8+j]; B lane: V[ks*32+l4*8+j][db*16+l15]
#pragma unroll
    for (int ks = 0; ks < 2; ++ks) {
      short8 pa = *reinterpret_cast<const short8*>(&Ps[w][0][ks][l15][l4 * 8]);
#pragma unroll
      for (int db = 0; db < 4; ++db)
        accg[db] = mfma16(pa,
                          *reinterpret_cast<const short8*>(&Vt[ks][db * 16 + l15][l4 * 8]),
                          accg[db]);
    }
#pragma unroll
    for (int ks = 0; ks < 2; ++ks) {
      short8 pa = *reinterpret_cast<const short8*>(&Ps[w][1][ks][l15][l4 * 8]);
#pragma unroll
      for (int db = 0; db < 4; ++db)
        accl[db] = mfma16(pa,
                          *reinterpret_cast<const short8*>(&Vt[ks][db * 16 + l15][l4 * 8]),
                          accl[db]);
    }
    __syncthreads();
  }
  // epilogue: O = acc / l, write to group-layout f32 buffers
#pragma unroll
  for (int r = 0; r < 4; ++r) {
    float ig = 1.f / lg[r];
    float il = ll[r] > 0.f ? 1.f / ll[r] : 0.f;
#pragma unroll
    for (int db = 0; db < 4; ++db) {
      size_t o = gbase + (size_t)(qrow + r) * 64 + db * 16 + l15;
      Xg[o] = accg[db][r] * ig;
      Xl[o] = accl[db][r] * il;
    }
  }
}

// ------- combine: gate, signed-sqrt, row L2-norm, cast bf16 -----------------
__global__ __launch_bounds__(256) void k_combine(const float* __restrict__ Xg,
                                                 const float* __restrict__ Xl,
                                                 const float* __restrict__ alphap,
                                                 unsigned short* __restrict__ xob) {
  int row = blockIdx.x, tid = threadIdx.x;
  int w = tid >> 6, l = tid & 63;
  size_t base = (size_t)row * 1024 + tid * 4;
  float a = 1.f / (1.f + __expf(-alphap[0]));
  float4 gx = *reinterpret_cast<const float4*>(Xg + base);
  float4 lx = *reinterpret_cast<const float4*>(Xl + base);
  float v[4];
  {
    float t0 = a * gx.x + (1.f - a) * lx.x;
    float t1 = a * gx.y + (1.f - a) * lx.y;
    float t2 = a * gx.z + (1.f - a) * lx.z;
    float t3 = a * gx.w + (1.f - a) * lx.w;
    v[0] = t0 >= 0.f ? sqrtf(t0) : -sqrtf(-t0);
    v[1] = t1 >= 0.f ? sqrtf(t1) : -sqrtf(-t1);
    v[2] = t2 >= 0.f ? sqrtf(t2) : -sqrtf(-t2);
    v[3] = t3 >= 0.f ? sqrtf(t3) : -sqrtf(-t3);
  }
  float ss = v[0] * v[0] + v[1] * v[1] + v[2] * v[2] + v[3] * v[3];
#pragma unroll
  for (int off = 1; off < 64; off <<= 1) ss += __shfl_xor(ss, off);
  __shared__ float wsum[4];
  if (l == 0) wsum[w] = ss;
  __syncthreads();
  float tot = wsum[0] + wsum[1] + wsum[2] + wsum[3];
  float scale = 1.f / fmaxf(sqrtf(tot), 1e-12f);
  ushort4 o;
  o.x = f2b(v[0] * scale); o.y = f2b(v[1] * scale);
  o.z = f2b(v[2] * scale); o.w = f2b(v[3] * scale);
  *reinterpret_cast<ushort4*>(xob + base) = o;
}

// ---------------------------------------------------------------------------
extern "C" void kernel_launch(void* const* d_in, const int* in_sizes, int n_in,
                              void* d_out, int out_size, void* d_ws, size_t ws_size,
                              hipStream_t stream) {
  const float* x     = (const float*)d_in[0];
  const int*   mask  = (const int*)d_in[1];
  const float* adj   = (const float*)d_in[2];
  const float* Wq    = (const float*)d_in[3];
  const float* bq    = (const float*)d_in[4];
  const float* Wk    = (const float*)d_in[5];
  const float* bk    = (const float*)d_in[6];
  const float* Wv    = (const float*)d_in[7];
  const float* bv    = (const float*)d_in[8];
  const float* Wo    = (const float*)d_in[9];
  const float* bo    = (const float*)d_in[10];
  const float* alpha = (const float*)d_in[11];
  float* out = (float*)d_out;
  char* ws = (char*)d_ws;

  unsigned short* xb    = (unsigned short*)(ws + 0);          //  8 MB
  unsigned short* WcatT = (unsigned short*)(ws + 8388608);    //  6 MB [n][k], Wq|Wk|Wv
  unsigned short* WoT   = (unsigned short*)(ws + 14680064);   //  2 MB
  unsigned short* Qb    = (unsigned short*)(ws + 16777216);   //  8 MB
  unsigned short* Kb    = (unsigned short*)(ws + 25165824);   //  8 MB
  unsigned short* Vb    = (unsigned short*)(ws + 33554432);   //  8 MB
  float*          Xg    = (float*)(ws + 41943040);            // 16 MB
  float*          Xl    = (float*)(ws + 58720256);            // 16 MB
  unsigned short* xob   = (unsigned short*)(ws + 75497472);   //  8 MB
  unsigned int*   AM    = (unsigned int*)(ws + 83886080);     //  4 MB

  k_cast_x<<<2048, 256, 0, stream>>>(x, xb);
  k_transW<<<dim3(16, 16, 4), 256, 0, stream>>>(Wq, Wk, Wv, Wo, WcatT, WoT);
  k_pack<<<1024, 256, 0, stream>>>(adj, mask, AM);
  k_gemm<0><<<dim3(32, 24), 256, 0, stream>>>(xb, WcatT, nullptr, Qb, Kb, Vb,
                                              bq, bk, bv, 4096, 3072, 1024);
  k_attn<<<dim3(16, 64), 256, 0, stream>>>(Qb, Kb, Vb, AM, Xg, Xl);
  k_combine<<<4096, 256, 0, stream>>>(Xg, Xl, alpha, xob);
  k_gemm<1><<<dim3(32, 8), 256, 0, stream>>>(xob, WoT, out, nullptr, nullptr,
                                             nullptr, bo, bo, bo, 4096, 1024, 1024);
}

// Round 5
// 234.914 us; speedup vs baseline: 1.2943x; 1.2943x over previous
//
#include <hip/hip_runtime.h>
#include <hip/hip_bf16.h>

// ---------------------------------------------------------------------------
// Fused dual-attention block (TCA_309237645935) for gfx950.  Round 5
// (identical to R4; R4 was an infra failure, source re-verified offline).
//
// ds_read_b64_tr_b16 decode (m156 reconciled): A' = addr+OFF; lane reads
// column (A'>>3)&15 of the 4x16 bf16 tile at A'&~127, elem j at +32B.
// Per-lane column must be encoded as l15*8 in bits [6:3].
//
// k_attn: no-max dual softmax (logits bounded), ones-column MFMA row sums,
// P^T tile + cvt_pk + tr_read, V via global_load_lds [4][64][16] subtiles +
// tr_read, AM uint4 repack, double-buffered K/V staging, 1 barrier/K-tile.
// ---------------------------------------------------------------------------

typedef __attribute__((ext_vector_type(8))) short short8;
typedef __attribute__((ext_vector_type(4))) float f32x4;
typedef __attribute__((ext_vector_type(2))) int i32x2;

__device__ __forceinline__ f32x4 mfma16(short8 a, short8 b, f32x4 c) {
  return __builtin_amdgcn_mfma_f32_16x16x32_bf16(a, b, c, 0, 0, 0);
}

__device__ __forceinline__ unsigned short f2b(float f) {
  __hip_bfloat16 h = __float2bfloat16(f);
  return *reinterpret_cast<unsigned short*>(&h);
}

__device__ __forceinline__ unsigned cvtpk(float lo, float hi) {
  unsigned r;
  asm("v_cvt_pk_bf16_f32 %0, %1, %2" : "=v"(r) : "v"(lo), "v"(hi));
  return r;
}

__device__ __forceinline__ float exp2h(float x) {
  float r;
  asm("v_exp_f32 %0, %1" : "=v"(r) : "v"(x));
  return r;
}

// LDS byte offset of a __shared__ object (addrspace(3) pointers are 32-bit).
__device__ __forceinline__ unsigned ldsoff(const void* p) {
  return (unsigned)(size_t)(const __attribute__((address_space(3))) char*)p;
}

// ds_read_b64_tr_b16, compile-time offset.
template <int OFF>
__device__ __forceinline__ i32x2 dstr(unsigned addr) {
  i32x2 d;
  asm volatile("ds_read_b64_tr_b16 %0, %1 offset:%c2"
               : "=v"(d) : "v"(addr), "i"(OFF) : "memory");
  return d;
}

__device__ __forceinline__ void gload_lds16(const void* g, void* l) {
  __builtin_amdgcn_global_load_lds(
      (const __attribute__((address_space(1))) void*)g,
      (__attribute__((address_space(3))) void*)l, 16, 0, 0);
}

// ---------------- cast x (f32 -> bf16), 8 elems/thread ----------------------
__global__ __launch_bounds__(256) void k_cast_x(const float* __restrict__ x,
                                                unsigned short* __restrict__ xb) {
  int i = (blockIdx.x * 256 + threadIdx.x) * 8;
  float4 a = *reinterpret_cast<const float4*>(x + i);
  float4 b = *reinterpret_cast<const float4*>(x + i + 4);
  short8 o;
  o[0] = (short)f2b(a.x); o[1] = (short)f2b(a.y);
  o[2] = (short)f2b(a.z); o[3] = (short)f2b(a.w);
  o[4] = (short)f2b(b.x); o[5] = (short)f2b(b.y);
  o[6] = (short)f2b(b.z); o[7] = (short)f2b(b.w);
  *reinterpret_cast<short8*>(xb + i) = o;
}

// ---------- transpose+cast weights: W[k][n] f32 -> WT[n][k] bf16 ------------
__global__ __launch_bounds__(256) void k_transW(const float* __restrict__ Wq,
                                                const float* __restrict__ Wk,
                                                const float* __restrict__ Wv,
                                                const float* __restrict__ Wo,
                                                unsigned short* __restrict__ WcatT,
                                                unsigned short* __restrict__ WoT) {
  int wsel = blockIdx.z;
  const float* src = wsel == 0 ? Wq : wsel == 1 ? Wk : wsel == 2 ? Wv : Wo;
  unsigned short* dst = (wsel < 3) ? (WcatT + (size_t)wsel * 1024 * 1024) : WoT;
  int k0 = blockIdx.x * 64, n0 = blockIdx.y * 64;
  __shared__ float tile[64][65];
  int tr = threadIdx.x >> 6, tc = threadIdx.x & 63;
#pragma unroll
  for (int i = 0; i < 16; ++i) {
    int r = i * 4 + tr;
    tile[r][tc] = src[(size_t)(k0 + r) * 1024 + n0 + tc];
  }
  __syncthreads();
#pragma unroll
  for (int i = 0; i < 16; ++i) {
    int r = i * 4 + tr;
    dst[(size_t)(n0 + r) * 1024 + k0 + tc] = f2b(tile[tc][r]);
  }
}

// ---- pack adj*log2e (bf16 hi) + mask bit (lo), REORDERED [q][kt][l15][cb] --
__global__ __launch_bounds__(256) void k_pack(const float* __restrict__ adj,
                                              const int* __restrict__ mask,
                                              unsigned int* __restrict__ AM) {
  const float L2E = 1.4426950408889634f;
  int i = (blockIdx.x * 256 + threadIdx.x) * 4;
  int q = i >> 10, c = i & 1023;
  float4 a = *reinterpret_cast<const float4*>(adj + i);
  int4 m = *reinterpret_cast<const int4*>(mask + i);
  unsigned B = (unsigned)(q * 1024) + ((c >> 6) * 64) + ((c & 15) * 4) + ((c >> 4) & 3);
  AM[B]      = ((unsigned)f2b(a.x * L2E) << 16) | (m.x != 0 ? 1u : 0u);
  AM[B + 4]  = ((unsigned)f2b(a.y * L2E) << 16) | (m.y != 0 ? 1u : 0u);
  AM[B + 8]  = ((unsigned)f2b(a.z * L2E) << 16) | (m.z != 0 ? 1u : 0u);
  AM[B + 12] = ((unsigned)f2b(a.w * L2E) << 16) | (m.w != 0 ? 1u : 0u);
}

// ---------------- m97-style bf16 GEMM: C = A(MxK) @ BT(NxK)^T + bias --------
template <int MODE>
__global__ __launch_bounds__(256) void k_gemm(
    const unsigned short* __restrict__ A, const unsigned short* __restrict__ BT,
    float* __restrict__ outF,
    unsigned short* __restrict__ oQ, unsigned short* __restrict__ oK,
    unsigned short* __restrict__ oV,
    const float* __restrict__ b0, const float* __restrict__ b1,
    const float* __restrict__ b2, int M, int N, int K) {
  __shared__ unsigned short As[128 * 32], Bs[128 * 32];
  const int tid = threadIdx.x;
  const int w = tid >> 6, l = tid & 63, l15 = l & 15, l4 = l >> 4;
  const int m0 = blockIdx.x * 128, n0 = blockIdx.y * 128;
  const int wm = (w >> 1) * 64, wn = (w & 1) * 64;
  f32x4 acc[4][4];
#pragma unroll
  for (int i = 0; i < 4; ++i)
#pragma unroll
    for (int j = 0; j < 4; ++j) acc[i][j] = f32x4{0.f, 0.f, 0.f, 0.f};

  const int nkt = K >> 5;
  for (int kt = 0; kt < nkt; ++kt) {
#pragma unroll
    for (int i = 0; i < 2; ++i) {
      int c = i * 256 + tid;
      gload_lds16(A + (size_t)(m0 + (c >> 2)) * K + kt * 32 + (c & 3) * 8,
                  (char*)As + c * 16);
      gload_lds16(BT + (size_t)(n0 + (c >> 2)) * K + kt * 32 + (c & 3) * 8,
                  (char*)Bs + c * 16);
    }
    __syncthreads();
    short8 af[4], bf[4];
#pragma unroll
    for (int i = 0; i < 4; ++i)
      af[i] = *reinterpret_cast<const short8*>(As + (wm + i * 16 + l15) * 32 + l4 * 8);
#pragma unroll
    for (int j = 0; j < 4; ++j)
      bf[j] = *reinterpret_cast<const short8*>(Bs + (wn + j * 16 + l15) * 32 + l4 * 8);
#pragma unroll
    for (int i = 0; i < 4; ++i)
#pragma unroll
      for (int j = 0; j < 4; ++j) acc[i][j] = mfma16(af[i], bf[j], acc[i][j]);
    __syncthreads();
  }
#pragma unroll
  for (int i = 0; i < 4; ++i)
#pragma unroll
    for (int j = 0; j < 4; ++j) {
      int gr0 = m0 + wm + i * 16 + l4 * 4;
      int gc = n0 + wn + j * 16 + l15;
      if (MODE == 0) {
        int mat = gc >> 10, nl = gc & 1023;
        const float* bp = mat == 0 ? b0 : mat == 1 ? b1 : b2;
        unsigned short* op = mat == 0 ? oQ : mat == 1 ? oK : oV;
        float bb = bp[nl];
#pragma unroll
        for (int r = 0; r < 4; ++r)
          op[(size_t)(gr0 + r) * 1024 + nl] = f2b(acc[i][j][r] + bb);
      } else {
        float bb = b0[gc];
#pragma unroll
        for (int r = 0; r < 4; ++r)
          outF[(size_t)(gr0 + r) * N + gc] = acc[i][j][r] + bb;
      }
    }
}

// ---------------- dual-softmax flash attention (no-max) ---------------------
// grid (64 groups, 16 q-tiles), 256 thr (4 waves), wave owns 16 q rows.
// Double-buffered K/V staging, 1 barrier per K-tile.
__global__ __launch_bounds__(256) void k_attn(
    const unsigned short* __restrict__ Qb, const unsigned short* __restrict__ Kb,
    const unsigned short* __restrict__ Vb, const unsigned int* __restrict__ AM,
    float* __restrict__ Xg, float* __restrict__ Xl) {
  const int g = blockIdx.x;
  const int q0 = blockIdx.y * 64;
  const int tid = threadIdx.x;
  const int w = tid >> 6, l = tid & 63, l15 = l & 15, l4 = l >> 4;

  __shared__ unsigned short Kt[2][2][64][32];   // [buf][dk][key][slot] XOR'd
  __shared__ unsigned short Vs[2][4][64][16];   // [buf][db][k][d&15] subtiled
  __shared__ unsigned short Pt[4][2][64][16];   // [wave][map][k][q] transposed

  const size_t gbase = (size_t)g << 16;
  const unsigned short* Qg = Qb + gbase;
  const unsigned short* Kg = Kb + gbase;
  const unsigned short* Vg = Vb + gbase;

  short8 qf[2];
  {
    const unsigned short* qp = Qg + (size_t)(q0 + w * 16 + l15) * 64 + l4 * 8;
    qf[0] = *reinterpret_cast<const short8*>(qp);
    qf[1] = *reinterpret_cast<const short8*>(qp + 32);
  }
  short8 onesf;
#pragma unroll
  for (int j = 0; j < 8; ++j) onesf[j] = (short)0x3F80;  // bf16 1.0

  f32x4 accg[4], accl[4];
#pragma unroll
  for (int d = 0; d < 4; ++d) {
    accg[d] = f32x4{0.f, 0.f, 0.f, 0.f};
    accl[d] = f32x4{0.f, 0.f, 0.f, 0.f};
  }
  f32x4 sumg = f32x4{0.f, 0.f, 0.f, 0.f}, suml = f32x4{0.f, 0.f, 0.f, 0.f};

  const int qrow = q0 + w * 16 + l4 * 4;  // + r
  const float NF2 = 0.04508422002778f;    // log2e / 32
  const uint4* AMr4 = (const uint4*)AM;   // [q][kt][l15][cb] as uint4
  const int kx8 = (l4 ^ ((l15 >> 1) & 3)) * 8;  // K slot swizzle

  // tr-read per-lane addresses: column encoded as l15*8 in bits [6:3].
  const unsigned ptw = ldsoff(&Pt[w][0][0][0]) + (unsigned)(l4 * 256 + l15 * 8);
  const unsigned vsb = ldsoff(&Vs[0][0][0][0]) + (unsigned)(l4 * 256 + l15 * 8);

  auto stage = [&](int b, int kk0) {
#pragma unroll
    for (int i = 0; i < 2; ++i) {
      int c = i * 256 + tid;
      int dk = c >> 8, key = (c >> 2) & 63, slot = c & 3;
      int ls = slot ^ ((key >> 1) & 3);
      gload_lds16(Kg + (size_t)(kk0 + key) * 64 + dk * 32 + ls * 8,
                  (char*)Kt + b * 8192 + c * 16);
    }
#pragma unroll
    for (int i = 0; i < 2; ++i) {
      int c = i * 256 + tid;
      int db = c >> 7, k = (c >> 1) & 63, h = c & 1;
      gload_lds16(Vg + (size_t)(kk0 + k) * 64 + db * 16 + h * 8,
                  (char*)Vs + b * 8192 + c * 16);
    }
  };

  stage(0, 0);
  __syncthreads();

  for (int kt = 0; kt < 16; ++kt) {
    const int b = kt & 1;
    if (kt < 15) stage(b ^ 1, (kt + 1) * 64);  // async prefetch next tile

    // --- AM: one coalesced uint4 per q-row ---------------------------------
    union { uint4 v; unsigned u[4]; } amu[4];
#pragma unroll
    for (int r = 0; r < 4; ++r)
      amu[r].v = AMr4[(size_t)(qrow + r) * 256 + kt * 16 + l15];

    // --- S = Q K^T ---------------------------------------------------------
    f32x4 accs[4];
#pragma unroll
    for (int cb = 0; cb < 4; ++cb) accs[cb] = f32x4{0.f, 0.f, 0.f, 0.f};
#pragma unroll
    for (int cb = 0; cb < 4; ++cb)
#pragma unroll
      for (int dk = 0; dk < 2; ++dk)
        accs[cb] = mfma16(
            qf[dk],
            *reinterpret_cast<const short8*>(&Kt[b][dk][cb * 16 + l15][kx8]),
            accs[cb]);

    // --- no-max dual softmax: p = 2^(S*nf2 + adj*l2e); pl = msk ? p : 0 ----
#pragma unroll
    for (int cb = 0; cb < 4; ++cb) {
      unsigned am0 = amu[0].u[cb], am1 = amu[1].u[cb];
      unsigned am2 = amu[2].u[cb], am3 = amu[3].u[cb];
      float e0 = exp2h(fmaf(accs[cb][0], NF2, __uint_as_float(am0 & 0xffff0000u)));
      float e1 = exp2h(fmaf(accs[cb][1], NF2, __uint_as_float(am1 & 0xffff0000u)));
      float e2 = exp2h(fmaf(accs[cb][2], NF2, __uint_as_float(am2 & 0xffff0000u)));
      float e3 = exp2h(fmaf(accs[cb][3], NF2, __uint_as_float(am3 & 0xffff0000u)));
      float z0 = (am0 & 1u) ? e0 : 0.f;
      float z1 = (am1 & 1u) ? e1 : 0.f;
      float z2 = (am2 & 1u) ? e2 : 0.f;
      float z3 = (am3 & 1u) ? e3 : 0.f;
      int krow = cb * 16 + l15;
      *reinterpret_cast<uint2*>(&Pt[w][0][krow][l4 * 4]) =
          make_uint2(cvtpk(e0, e1), cvtpk(e2, e3));
      *reinterpret_cast<uint2*>(&Pt[w][1][krow][l4 * 4]) =
          make_uint2(cvtpk(z0, z1), cvtpk(z2, z3));
    }
    asm volatile("s_waitcnt lgkmcnt(0)" ::: "memory");  // P writes visible

    // --- PV + ones-column row sums (tr_read P and V) -----------------------
    const unsigned vb = vsb + (unsigned)(b << 13);
#pragma unroll
    for (int ks = 0; ks < 2; ++ks) {
      union { short8 s; i32x2 d[2]; } vf[4], pg, pl;
      if (ks == 0) {
#pragma unroll
        for (int db = 0; db < 4; ++db) {
          vf[db].d[0] = dstr<0 * 1024 + 0>(vb + db * 2048);
          vf[db].d[1] = dstr<0 * 1024 + 128>(vb + db * 2048);
        }
        pg.d[0] = dstr<0>(ptw);        pg.d[1] = dstr<128>(ptw);
        pl.d[0] = dstr<2048>(ptw);     pl.d[1] = dstr<2048 + 128>(ptw);
      } else {
#pragma unroll
        for (int db = 0; db < 4; ++db) {
          vf[db].d[0] = dstr<1 * 1024 + 0>(vb + db * 2048);
          vf[db].d[1] = dstr<1 * 1024 + 128>(vb + db * 2048);
        }
        pg.d[0] = dstr<1024>(ptw);     pg.d[1] = dstr<1024 + 128>(ptw);
        pl.d[0] = dstr<2048 + 1024>(ptw);
        pl.d[1] = dstr<2048 + 1024 + 128>(ptw);
      }
      asm volatile("s_waitcnt lgkmcnt(0)" ::: "memory");
      __builtin_amdgcn_sched_barrier(0);
#pragma unroll
      for (int db = 0; db < 4; ++db) {
        accg[db] = mfma16(pg.s, vf[db].s, accg[db]);
        accl[db] = mfma16(pl.s, vf[db].s, accl[db]);
      }
      sumg = mfma16(pg.s, onesf, sumg);
      suml = mfma16(pl.s, onesf, suml);
    }
    __syncthreads();
  }

  // --- epilogue: O = acc / rowsum ------------------------------------------
#pragma unroll
  for (int r = 0; r < 4; ++r) {
    float ig = 1.f / sumg[r];
    float il = suml[r] > 0.f ? 1.f / suml[r] : 0.f;
#pragma unroll
    for (int db = 0; db < 4; ++db) {
      size_t o = gbase + (size_t)(qrow + r) * 64 + db * 16 + l15;
      Xg[o] = accg[db][r] * ig;
      Xl[o] = accl[db][r] * il;
    }
  }
}

// ------- combine: gate, signed-sqrt, row L2-norm, cast bf16 -----------------
__global__ __launch_bounds__(256) void k_combine(const float* __restrict__ Xg,
                                                 const float* __restrict__ Xl,
                                                 const float* __restrict__ alphap,
                                                 unsigned short* __restrict__ xob) {
  int row = blockIdx.x, tid = threadIdx.x;
  int w = tid >> 6, l = tid & 63;
  size_t base = (size_t)row * 1024 + tid * 4;
  float a = 1.f / (1.f + __expf(-alphap[0]));
  float4 gx = *reinterpret_cast<const float4*>(Xg + base);
  float4 lx = *reinterpret_cast<const float4*>(Xl + base);
  float v[4];
  {
    float t0 = a * gx.x + (1.f - a) * lx.x;
    float t1 = a * gx.y + (1.f - a) * lx.y;
    float t2 = a * gx.z + (1.f - a) * lx.z;
    float t3 = a * gx.w + (1.f - a) * lx.w;
    v[0] = t0 >= 0.f ? sqrtf(t0) : -sqrtf(-t0);
    v[1] = t1 >= 0.f ? sqrtf(t1) : -sqrtf(-t1);
    v[2] = t2 >= 0.f ? sqrtf(t2) : -sqrtf(-t2);
    v[3] = t3 >= 0.f ? sqrtf(t3) : -sqrtf(-t3);
  }
  float ss = v[0] * v[0] + v[1] * v[1] + v[2] * v[2] + v[3] * v[3];
#pragma unroll
  for (int off = 1; off < 64; off <<= 1) ss += __shfl_xor(ss, off);
  __shared__ float wsum[4];
  if (l == 0) wsum[w] = ss;
  __syncthreads();
  float tot = wsum[0] + wsum[1] + wsum[2] + wsum[3];
  float scale = 1.f / fmaxf(sqrtf(tot), 1e-12f);
  ushort4 o;
  o.x = f2b(v[0] * scale); o.y = f2b(v[1] * scale);
  o.z = f2b(v[2] * scale); o.w = f2b(v[3] * scale);
  *reinterpret_cast<ushort4*>(xob + base) = o;
}

// ---------------------------------------------------------------------------
extern "C" void kernel_launch(void* const* d_in, const int* in_sizes, int n_in,
                              void* d_out, int out_size, void* d_ws, size_t ws_size,
                              hipStream_t stream) {
  const float* x     = (const float*)d_in[0];
  const int*   mask  = (const int*)d_in[1];
  const float* adj   = (const float*)d_in[2];
  const float* Wq    = (const float*)d_in[3];
  const float* bq    = (const float*)d_in[4];
  const float* Wk    = (const float*)d_in[5];
  const float* bk    = (const float*)d_in[6];
  const float* Wv    = (const float*)d_in[7];
  const float* bv    = (const float*)d_in[8];
  const float* Wo    = (const float*)d_in[9];
  const float* bo    = (const float*)d_in[10];
  const float* alpha = (const float*)d_in[11];
  float* out = (float*)d_out;
  char* ws = (char*)d_ws;

  unsigned short* xb    = (unsigned short*)(ws + 0);          //  8 MB
  unsigned short* WcatT = (unsigned short*)(ws + 8388608);    //  6 MB
  unsigned short* WoT   = (unsigned short*)(ws + 14680064);   //  2 MB
  unsigned short* Qb    = (unsigned short*)(ws + 16777216);   //  8 MB
  unsigned short* Kb    = (unsigned short*)(ws + 25165824);   //  8 MB
  unsigned short* Vb    = (unsigned short*)(ws + 33554432);   //  8 MB
  float*          Xg    = (float*)(ws + 41943040);            // 16 MB
  float*          Xl    = (float*)(ws + 58720256);            // 16 MB
  unsigned short* xob   = (unsigned short*)(ws + 75497472);   //  8 MB
  unsigned int*   AM    = (unsigned int*)(ws + 83886080);     //  4 MB

  k_cast_x<<<2048, 256, 0, stream>>>(x, xb);
  k_transW<<<dim3(16, 16, 4), 256, 0, stream>>>(Wq, Wk, Wv, Wo, WcatT, WoT);
  k_pack<<<1024, 256, 0, stream>>>(adj, mask, AM);
  k_gemm<0><<<dim3(32, 24), 256, 0, stream>>>(xb, WcatT, nullptr, Qb, Kb, Vb,
                                              bq, bk, bv, 4096, 3072, 1024);
  k_attn<<<dim3(64, 16), 256, 0, stream>>>(Qb, Kb, Vb, AM, Xg, Xl);
  k_combine<<<4096, 256, 0, stream>>>(Xg, Xl, alpha, xob);
  k_gemm<1><<<dim3(32, 8), 256, 0, stream>>>(xob, WoT, out, nullptr, nullptr,
                                             nullptr, bo, bo, bo, 4096, 1024, 1024);
}

// Round 6
// 231.980 us; speedup vs baseline: 1.3107x; 1.0126x over previous
//
#include <hip/hip_runtime.h>
#include <hip/hip_bf16.h>

// ---------------------------------------------------------------------------
// Fused dual-attention block (TCA_309237645935) for gfx950.  Round 6.
//
// vs R5: k_attn restructured to 128 q-rows/block (grid 64x8, fully resident
// 2 blocks/CU).  Each wave owns TWO independent 16-row subtiles:
//  - K-frag LDS reads + K/V staging + barriers shared across subtiles
//  - two independent QK^T/softmax/PV chains per wave -> 2x ILP for latency
//    hiding at unchanged occupancy.
// All verified addressing from R5 kept byte-identical (tr_read column decode
// l15*8 in bits[6:3]; K slot-XOR; AM [q][kt][l15][cb] uint4 pack; Pt offsets).
// ---------------------------------------------------------------------------

typedef __attribute__((ext_vector_type(8))) short short8;
typedef __attribute__((ext_vector_type(4))) float f32x4;
typedef __attribute__((ext_vector_type(2))) int i32x2;

__device__ __forceinline__ f32x4 mfma16(short8 a, short8 b, f32x4 c) {
  return __builtin_amdgcn_mfma_f32_16x16x32_bf16(a, b, c, 0, 0, 0);
}

__device__ __forceinline__ unsigned short f2b(float f) {
  __hip_bfloat16 h = __float2bfloat16(f);
  return *reinterpret_cast<unsigned short*>(&h);
}

__device__ __forceinline__ unsigned cvtpk(float lo, float hi) {
  unsigned r;
  asm("v_cvt_pk_bf16_f32 %0, %1, %2" : "=v"(r) : "v"(lo), "v"(hi));
  return r;
}

__device__ __forceinline__ float exp2h(float x) {
  float r;
  asm("v_exp_f32 %0, %1" : "=v"(r) : "v"(x));
  return r;
}

// LDS byte offset of a __shared__ object (addrspace(3) pointers are 32-bit).
__device__ __forceinline__ unsigned ldsoff(const void* p) {
  return (unsigned)(size_t)(const __attribute__((address_space(3))) char*)p;
}

// ds_read_b64_tr_b16, compile-time offset.  Decode: A' = addr+OFF; lane reads
// column (A'>>3)&15 of the 4x16 bf16 tile at A'&~127, elem j at +32B.
template <int OFF>
__device__ __forceinline__ i32x2 dstr(unsigned addr) {
  i32x2 d;
  asm volatile("ds_read_b64_tr_b16 %0, %1 offset:%c2"
               : "=v"(d) : "v"(addr), "i"(OFF) : "memory");
  return d;
}

__device__ __forceinline__ void gload_lds16(const void* g, void* l) {
  __builtin_amdgcn_global_load_lds(
      (const __attribute__((address_space(1))) void*)g,
      (__attribute__((address_space(3))) void*)l, 16, 0, 0);
}

// ---------------- cast x (f32 -> bf16), 8 elems/thread ----------------------
__global__ __launch_bounds__(256) void k_cast_x(const float* __restrict__ x,
                                                unsigned short* __restrict__ xb) {
  int i = (blockIdx.x * 256 + threadIdx.x) * 8;
  float4 a = *reinterpret_cast<const float4*>(x + i);
  float4 b = *reinterpret_cast<const float4*>(x + i + 4);
  short8 o;
  o[0] = (short)f2b(a.x); o[1] = (short)f2b(a.y);
  o[2] = (short)f2b(a.z); o[3] = (short)f2b(a.w);
  o[4] = (short)f2b(b.x); o[5] = (short)f2b(b.y);
  o[6] = (short)f2b(b.z); o[7] = (short)f2b(b.w);
  *reinterpret_cast<short8*>(xb + i) = o;
}

// ---------- transpose+cast weights: W[k][n] f32 -> WT[n][k] bf16 ------------
__global__ __launch_bounds__(256) void k_transW(const float* __restrict__ Wq,
                                                const float* __restrict__ Wk,
                                                const float* __restrict__ Wv,
                                                const float* __restrict__ Wo,
                                                unsigned short* __restrict__ WcatT,
                                                unsigned short* __restrict__ WoT) {
  int wsel = blockIdx.z;
  const float* src = wsel == 0 ? Wq : wsel == 1 ? Wk : wsel == 2 ? Wv : Wo;
  unsigned short* dst = (wsel < 3) ? (WcatT + (size_t)wsel * 1024 * 1024) : WoT;
  int k0 = blockIdx.x * 64, n0 = blockIdx.y * 64;
  __shared__ float tile[64][65];
  int tr = threadIdx.x >> 6, tc = threadIdx.x & 63;
#pragma unroll
  for (int i = 0; i < 16; ++i) {
    int r = i * 4 + tr;
    tile[r][tc] = src[(size_t)(k0 + r) * 1024 + n0 + tc];
  }
  __syncthreads();
#pragma unroll
  for (int i = 0; i < 16; ++i) {
    int r = i * 4 + tr;
    dst[(size_t)(n0 + r) * 1024 + k0 + tc] = f2b(tile[tc][r]);
  }
}

// ---- pack adj*log2e (bf16 hi) + mask bit (lo), REORDERED [q][kt][l15][cb] --
__global__ __launch_bounds__(256) void k_pack(const float* __restrict__ adj,
                                              const int* __restrict__ mask,
                                              unsigned int* __restrict__ AM) {
  const float L2E = 1.4426950408889634f;
  int i = (blockIdx.x * 256 + threadIdx.x) * 4;
  int q = i >> 10, c = i & 1023;
  float4 a = *reinterpret_cast<const float4*>(adj + i);
  int4 m = *reinterpret_cast<const int4*>(mask + i);
  unsigned B = (unsigned)(q * 1024) + ((c >> 6) * 64) + ((c & 15) * 4) + ((c >> 4) & 3);
  AM[B]      = ((unsigned)f2b(a.x * L2E) << 16) | (m.x != 0 ? 1u : 0u);
  AM[B + 4]  = ((unsigned)f2b(a.y * L2E) << 16) | (m.y != 0 ? 1u : 0u);
  AM[B + 8]  = ((unsigned)f2b(a.z * L2E) << 16) | (m.z != 0 ? 1u : 0u);
  AM[B + 12] = ((unsigned)f2b(a.w * L2E) << 16) | (m.w != 0 ? 1u : 0u);
}

// ---------------- m97-style bf16 GEMM: C = A(MxK) @ BT(NxK)^T + bias --------
template <int MODE>
__global__ __launch_bounds__(256) void k_gemm(
    const unsigned short* __restrict__ A, const unsigned short* __restrict__ BT,
    float* __restrict__ outF,
    unsigned short* __restrict__ oQ, unsigned short* __restrict__ oK,
    unsigned short* __restrict__ oV,
    const float* __restrict__ b0, const float* __restrict__ b1,
    const float* __restrict__ b2, int M, int N, int K) {
  __shared__ unsigned short As[128 * 32], Bs[128 * 32];
  const int tid = threadIdx.x;
  const int w = tid >> 6, l = tid & 63, l15 = l & 15, l4 = l >> 4;
  const int m0 = blockIdx.x * 128, n0 = blockIdx.y * 128;
  const int wm = (w >> 1) * 64, wn = (w & 1) * 64;
  f32x4 acc[4][4];
#pragma unroll
  for (int i = 0; i < 4; ++i)
#pragma unroll
    for (int j = 0; j < 4; ++j) acc[i][j] = f32x4{0.f, 0.f, 0.f, 0.f};

  const int nkt = K >> 5;
  for (int kt = 0; kt < nkt; ++kt) {
#pragma unroll
    for (int i = 0; i < 2; ++i) {
      int c = i * 256 + tid;
      gload_lds16(A + (size_t)(m0 + (c >> 2)) * K + kt * 32 + (c & 3) * 8,
                  (char*)As + c * 16);
      gload_lds16(BT + (size_t)(n0 + (c >> 2)) * K + kt * 32 + (c & 3) * 8,
                  (char*)Bs + c * 16);
    }
    __syncthreads();
    short8 af[4], bf[4];
#pragma unroll
    for (int i = 0; i < 4; ++i)
      af[i] = *reinterpret_cast<const short8*>(As + (wm + i * 16 + l15) * 32 + l4 * 8);
#pragma unroll
    for (int j = 0; j < 4; ++j)
      bf[j] = *reinterpret_cast<const short8*>(Bs + (wn + j * 16 + l15) * 32 + l4 * 8);
#pragma unroll
    for (int i = 0; i < 4; ++i)
#pragma unroll
      for (int j = 0; j < 4; ++j) acc[i][j] = mfma16(af[i], bf[j], acc[i][j]);
    __syncthreads();
  }
#pragma unroll
  for (int i = 0; i < 4; ++i)
#pragma unroll
    for (int j = 0; j < 4; ++j) {
      int gr0 = m0 + wm + i * 16 + l4 * 4;
      int gc = n0 + wn + j * 16 + l15;
      if (MODE == 0) {
        int mat = gc >> 10, nl = gc & 1023;
        const float* bp = mat == 0 ? b0 : mat == 1 ? b1 : b2;
        unsigned short* op = mat == 0 ? oQ : mat == 1 ? oK : oV;
        float bb = bp[nl];
#pragma unroll
        for (int r = 0; r < 4; ++r)
          op[(size_t)(gr0 + r) * 1024 + nl] = f2b(acc[i][j][r] + bb);
      } else {
        float bb = b0[gc];
#pragma unroll
        for (int r = 0; r < 4; ++r)
          outF[(size_t)(gr0 + r) * N + gc] = acc[i][j][r] + bb;
      }
    }
}

// ---------------- dual-softmax flash attention (no-max) ---------------------
// grid (64 groups, 8 q-tiles of 128 rows), 256 thr (4 waves).
// Each wave: 32 q rows = 2 independent 16-row subtiles (2x ILP).
// Double-buffered K/V staging, 1 barrier per K-tile; Pt reused per subtile.
__global__ __launch_bounds__(256, 2) void k_attn(
    const unsigned short* __restrict__ Qb, const unsigned short* __restrict__ Kb,
    const unsigned short* __restrict__ Vb, const unsigned int* __restrict__ AM,
    float* __restrict__ Xg, float* __restrict__ Xl) {
  const int g = blockIdx.x;
  const int q0 = blockIdx.y * 128;
  const int tid = threadIdx.x;
  const int w = tid >> 6, l = tid & 63, l15 = l & 15, l4 = l >> 4;

  __shared__ unsigned short Kt[2][2][64][32];   // [buf][dk][key][slot] XOR'd
  __shared__ unsigned short Vs[2][4][64][16];   // [buf][db][k][d&15] subtiled
  __shared__ unsigned short Pt[4][2][64][16];   // [wave][map][k][q] transposed

  const size_t gbase = (size_t)g << 16;
  const unsigned short* Qg = Qb + gbase;
  const unsigned short* Kg = Kb + gbase;
  const unsigned short* Vg = Vb + gbase;

  // Q frags: subtile s rows = q0 + w*32 + s*16 + l15
  short8 qf[2][2];
#pragma unroll
  for (int s = 0; s < 2; ++s) {
    const unsigned short* qp =
        Qg + (size_t)(q0 + w * 32 + s * 16 + l15) * 64 + l4 * 8;
    qf[s][0] = *reinterpret_cast<const short8*>(qp);
    qf[s][1] = *reinterpret_cast<const short8*>(qp + 32);
  }
  short8 onesf;
#pragma unroll
  for (int j = 0; j < 8; ++j) onesf[j] = (short)0x3F80;  // bf16 1.0

  f32x4 accg[2][4], accl[2][4], sumg[2], suml[2];
#pragma unroll
  for (int s = 0; s < 2; ++s) {
    sumg[s] = f32x4{0.f, 0.f, 0.f, 0.f};
    suml[s] = f32x4{0.f, 0.f, 0.f, 0.f};
#pragma unroll
    for (int d = 0; d < 4; ++d) {
      accg[s][d] = f32x4{0.f, 0.f, 0.f, 0.f};
      accl[s][d] = f32x4{0.f, 0.f, 0.f, 0.f};
    }
  }

  const int qrowb = q0 + w * 32 + l4 * 4;  // + s*16 + r
  const float NF2 = 0.04508422002778f;     // log2e / 32
  const uint4* AMr4 = (const uint4*)AM;    // [q][kt][l15][cb] as uint4
  const int kx8 = (l4 ^ ((l15 >> 1) & 3)) * 8;  // K slot swizzle

  // tr-read per-lane addresses: column encoded as l15*8 in bits [6:3].
  const unsigned ptw = ldsoff(&Pt[w][0][0][0]) + (unsigned)(l4 * 256 + l15 * 8);
  const unsigned vsb = ldsoff(&Vs[0][0][0][0]) + (unsigned)(l4 * 256 + l15 * 8);

  auto stage = [&](int b, int kk0) {
#pragma unroll
    for (int i = 0; i < 2; ++i) {
      int c = i * 256 + tid;
      int dk = c >> 8, key = (c >> 2) & 63, slot = c & 3;
      int ls = slot ^ ((key >> 1) & 3);
      gload_lds16(Kg + (size_t)(kk0 + key) * 64 + dk * 32 + ls * 8,
                  (char*)Kt + b * 8192 + c * 16);
    }
#pragma unroll
    for (int i = 0; i < 2; ++i) {
      int c = i * 256 + tid;
      int db = c >> 7, k = (c >> 1) & 63, h = c & 1;
      gload_lds16(Vg + (size_t)(kk0 + k) * 64 + db * 16 + h * 8,
                  (char*)Vs + b * 8192 + c * 16);
    }
  };

  stage(0, 0);
  __syncthreads();

  for (int kt = 0; kt < 16; ++kt) {
    const int b = kt & 1;
    if (kt < 15) stage(b ^ 1, (kt + 1) * 64);  // async prefetch next tile

    // --- K frags once, shared by both subtiles -----------------------------
    short8 kf[4][2];
#pragma unroll
    for (int cb = 0; cb < 4; ++cb)
#pragma unroll
      for (int dk = 0; dk < 2; ++dk)
        kf[cb][dk] =
            *reinterpret_cast<const short8*>(&Kt[b][dk][cb * 16 + l15][kx8]);

    // --- S = Q K^T, both subtiles (8 independent chains) -------------------
    f32x4 accs[2][4];
#pragma unroll
    for (int s = 0; s < 2; ++s)
#pragma unroll
      for (int cb = 0; cb < 4; ++cb) accs[s][cb] = f32x4{0.f, 0.f, 0.f, 0.f};
#pragma unroll
    for (int cb = 0; cb < 4; ++cb)
#pragma unroll
      for (int s = 0; s < 2; ++s)
#pragma unroll
        for (int dk = 0; dk < 2; ++dk)
          accs[s][cb] = mfma16(qf[s][dk], kf[cb][dk], accs[s][cb]);

    const unsigned vb = vsb + (unsigned)(b << 13);

    // --- per subtile: softmax -> P^T -> PV ---------------------------------
#pragma unroll
    for (int s = 0; s < 2; ++s) {
      union { uint4 v; unsigned u[4]; } amu[4];
#pragma unroll
      for (int r = 0; r < 4; ++r)
        amu[r].v = AMr4[(size_t)(qrowb + s * 16 + r) * 256 + kt * 16 + l15];

#pragma unroll
      for (int cb = 0; cb < 4; ++cb) {
        unsigned am0 = amu[0].u[cb], am1 = amu[1].u[cb];
        unsigned am2 = amu[2].u[cb], am3 = amu[3].u[cb];
        float e0 = exp2h(fmaf(accs[s][cb][0], NF2, __uint_as_float(am0 & 0xffff0000u)));
        float e1 = exp2h(fmaf(accs[s][cb][1], NF2, __uint_as_float(am1 & 0xffff0000u)));
        float e2 = exp2h(fmaf(accs[s][cb][2], NF2, __uint_as_float(am2 & 0xffff0000u)));
        float e3 = exp2h(fmaf(accs[s][cb][3], NF2, __uint_as_float(am3 & 0xffff0000u)));
        float z0 = (am0 & 1u) ? e0 : 0.f;
        float z1 = (am1 & 1u) ? e1 : 0.f;
        float z2 = (am2 & 1u) ? e2 : 0.f;
        float z3 = (am3 & 1u) ? e3 : 0.f;
        int krow = cb * 16 + l15;
        *reinterpret_cast<uint2*>(&Pt[w][0][krow][l4 * 4]) =
            make_uint2(cvtpk(e0, e1), cvtpk(e2, e3));
        *reinterpret_cast<uint2*>(&Pt[w][1][krow][l4 * 4]) =
            make_uint2(cvtpk(z0, z1), cvtpk(z2, z3));
      }
      asm volatile("s_waitcnt lgkmcnt(0)" ::: "memory");  // P writes visible

#pragma unroll
      for (int ks = 0; ks < 2; ++ks) {
        union { short8 s8; i32x2 d[2]; } vf[4], pg, pl;
        if (ks == 0) {
#pragma unroll
          for (int db = 0; db < 4; ++db) {
            vf[db].d[0] = dstr<0>(vb + db * 2048);
            vf[db].d[1] = dstr<128>(vb + db * 2048);
          }
          pg.d[0] = dstr<0>(ptw);        pg.d[1] = dstr<128>(ptw);
          pl.d[0] = dstr<2048>(ptw);     pl.d[1] = dstr<2048 + 128>(ptw);
        } else {
#pragma unroll
          for (int db = 0; db < 4; ++db) {
            vf[db].d[0] = dstr<1024>(vb + db * 2048);
            vf[db].d[1] = dstr<1024 + 128>(vb + db * 2048);
          }
          pg.d[0] = dstr<1024>(ptw);     pg.d[1] = dstr<1024 + 128>(ptw);
          pl.d[0] = dstr<2048 + 1024>(ptw);
          pl.d[1] = dstr<2048 + 1024 + 128>(ptw);
        }
        asm volatile("s_waitcnt lgkmcnt(0)" ::: "memory");
        __builtin_amdgcn_sched_barrier(0);
#pragma unroll
        for (int db = 0; db < 4; ++db) {
          accg[s][db] = mfma16(pg.s8, vf[db].s8, accg[s][db]);
          accl[s][db] = mfma16(pl.s8, vf[db].s8, accl[s][db]);
        }
        sumg[s] = mfma16(pg.s8, onesf, sumg[s]);
        suml[s] = mfma16(pl.s8, onesf, suml[s]);
      }
    }
    __syncthreads();
  }

  // --- epilogue: O = acc / rowsum ------------------------------------------
#pragma unroll
  for (int s = 0; s < 2; ++s)
#pragma unroll
    for (int r = 0; r < 4; ++r) {
      float ig = 1.f / sumg[s][r];
      float il = suml[s][r] > 0.f ? 1.f / suml[s][r] : 0.f;
#pragma unroll
      for (int db = 0; db < 4; ++db) {
        size_t o = gbase + (size_t)(qrowb + s * 16 + r) * 64 + db * 16 + l15;
        Xg[o] = accg[s][db][r] * ig;
        Xl[o] = accl[s][db][r] * il;
      }
    }
}

// ------- combine: gate, signed-sqrt, row L2-norm, cast bf16 -----------------
__global__ __launch_bounds__(256) void k_combine(const float* __restrict__ Xg,
                                                 const float* __restrict__ Xl,
                                                 const float* __restrict__ alphap,
                                                 unsigned short* __restrict__ xob) {
  int row = blockIdx.x, tid = threadIdx.x;
  int w = tid >> 6, l = tid & 63;
  size_t base = (size_t)row * 1024 + tid * 4;
  float a = 1.f / (1.f + __expf(-alphap[0]));
  float4 gx = *reinterpret_cast<const float4*>(Xg + base);
  float4 lx = *reinterpret_cast<const float4*>(Xl + base);
  float v[4];
  {
    float t0 = a * gx.x + (1.f - a) * lx.x;
    float t1 = a * gx.y + (1.f - a) * lx.y;
    float t2 = a * gx.z + (1.f - a) * lx.z;
    float t3 = a * gx.w + (1.f - a) * lx.w;
    v[0] = t0 >= 0.f ? sqrtf(t0) : -sqrtf(-t0);
    v[1] = t1 >= 0.f ? sqrtf(t1) : -sqrtf(-t1);
    v[2] = t2 >= 0.f ? sqrtf(t2) : -sqrtf(-t2);
    v[3] = t3 >= 0.f ? sqrtf(t3) : -sqrtf(-t3);
  }
  float ss = v[0] * v[0] + v[1] * v[1] + v[2] * v[2] + v[3] * v[3];
#pragma unroll
  for (int off = 1; off < 64; off <<= 1) ss += __shfl_xor(ss, off);
  __shared__ float wsum[4];
  if (l == 0) wsum[w] = ss;
  __syncthreads();
  float tot = wsum[0] + wsum[1] + wsum[2] + wsum[3];
  float scale = 1.f / fmaxf(sqrtf(tot), 1e-12f);
  ushort4 o;
  o.x = f2b(v[0] * scale); o.y = f2b(v[1] * scale);
  o.z = f2b(v[2] * scale); o.w = f2b(v[3] * scale);
  *reinterpret_cast<ushort4*>(xob + base) = o;
}

// ---------------------------------------------------------------------------
extern "C" void kernel_launch(void* const* d_in, const int* in_sizes, int n_in,
                              void* d_out, int out_size, void* d_ws, size_t ws_size,
                              hipStream_t stream) {
  const float* x     = (const float*)d_in[0];
  const int*   mask  = (const int*)d_in[1];
  const float* adj   = (const float*)d_in[2];
  const float* Wq    = (const float*)d_in[3];
  const float* bq    = (const float*)d_in[4];
  const float* Wk    = (const float*)d_in[5];
  const float* bk    = (const float*)d_in[6];
  const float* Wv    = (const float*)d_in[7];
  const float* bv    = (const float*)d_in[8];
  const float* Wo    = (const float*)d_in[9];
  const float* bo    = (const float*)d_in[10];
  const float* alpha = (const float*)d_in[11];
  float* out = (float*)d_out;
  char* ws = (char*)d_ws;

  unsigned short* xb    = (unsigned short*)(ws + 0);          //  8 MB
  unsigned short* WcatT = (unsigned short*)(ws + 8388608);    //  6 MB
  unsigned short* WoT   = (unsigned short*)(ws + 14680064);   //  2 MB
  unsigned short* Qb    = (unsigned short*)(ws + 16777216);   //  8 MB
  unsigned short* Kb    = (unsigned short*)(ws + 25165824);   //  8 MB
  unsigned short* Vb    = (unsigned short*)(ws + 33554432);   //  8 MB
  float*          Xg    = (float*)(ws + 41943040);            // 16 MB
  float*          Xl    = (float*)(ws + 58720256);            // 16 MB
  unsigned short* xob   = (unsigned short*)(ws + 75497472);   //  8 MB
  unsigned int*   AM    = (unsigned int*)(ws + 83886080);     //  4 MB

  k_cast_x<<<2048, 256, 0, stream>>>(x, xb);
  k_transW<<<dim3(16, 16, 4), 256, 0, stream>>>(Wq, Wk, Wv, Wo, WcatT, WoT);
  k_pack<<<1024, 256, 0, stream>>>(adj, mask, AM);
  k_gemm<0><<<dim3(32, 24), 256, 0, stream>>>(xb, WcatT, nullptr, Qb, Kb, Vb,
                                              bq, bk, bv, 4096, 3072, 1024);
  k_attn<<<dim3(64, 8), 256, 0, stream>>>(Qb, Kb, Vb, AM, Xg, Xl);
  k_combine<<<4096, 256, 0, stream>>>(Xg, Xl, alpha, xob);
  k_gemm<1><<<dim3(32, 8), 256, 0, stream>>>(xob, WoT, out, nullptr, nullptr,
                                             nullptr, bo, bo, bo, 4096, 1024, 1024);
}

// Round 7
// 230.500 us; speedup vs baseline: 1.3191x; 1.0064x over previous
//
#include <hip/hip_runtime.h>
#include <hip/hip_bf16.h>

// ---------------------------------------------------------------------------
// Fused dual-attention block (TCA_309237645935) for gfx950.  Round 7.
//
// vs R6: k_attn P matrix never touches LDS.  Swapped QK^T (mfma(K,Q)) puts
// q=l15 in the S^T output, matching the PV A-operand layout; the key->row
// permutation key = 8*(row>>2)+(row&3)+4*(cb&1)+32*(cb>>1) makes the cvt_pk
// pairs land exactly in PV A-frag register order (no lane moves, no P-LDS).
// AM repacked [kt][h][g][q][8].  LDS 32KB, grid 64x16 (4 blocks/CU),
// launch_bounds(256,4) -> target 16 waves/CU.
// ---------------------------------------------------------------------------

typedef __attribute__((ext_vector_type(8))) short short8;
typedef __attribute__((ext_vector_type(4))) float f32x4;
typedef __attribute__((ext_vector_type(2))) int i32x2;

__device__ __forceinline__ f32x4 mfma16(short8 a, short8 b, f32x4 c) {
  return __builtin_amdgcn_mfma_f32_16x16x32_bf16(a, b, c, 0, 0, 0);
}

__device__ __forceinline__ unsigned short f2b(float f) {
  __hip_bfloat16 h = __float2bfloat16(f);
  return *reinterpret_cast<unsigned short*>(&h);
}

__device__ __forceinline__ unsigned cvtpk(float lo, float hi) {
  unsigned r;
  asm("v_cvt_pk_bf16_f32 %0, %1, %2" : "=v"(r) : "v"(lo), "v"(hi));
  return r;
}

__device__ __forceinline__ float exp2h(float x) {
  float r;
  asm("v_exp_f32 %0, %1" : "=v"(r) : "v"(x));
  return r;
}

// LDS byte offset of a __shared__ object (addrspace(3) pointers are 32-bit).
__device__ __forceinline__ unsigned ldsoff(const void* p) {
  return (unsigned)(size_t)(const __attribute__((address_space(3))) char*)p;
}

// ds_read_b64_tr_b16: A' = addr+OFF; lane reads column (A'>>3)&15 of the
// 4x16 bf16 tile at A'&~127, elem j at +32B.  (Verified R5.)
template <int OFF>
__device__ __forceinline__ i32x2 dstr(unsigned addr) {
  i32x2 d;
  asm volatile("ds_read_b64_tr_b16 %0, %1 offset:%c2"
               : "=v"(d) : "v"(addr), "i"(OFF) : "memory");
  return d;
}

__device__ __forceinline__ void gload_lds16(const void* g, void* l) {
  __builtin_amdgcn_global_load_lds(
      (const __attribute__((address_space(1))) void*)g,
      (__attribute__((address_space(3))) void*)l, 16, 0, 0);
}

// ---------------- cast x (f32 -> bf16), 8 elems/thread ----------------------
__global__ __launch_bounds__(256) void k_cast_x(const float* __restrict__ x,
                                                unsigned short* __restrict__ xb) {
  int i = (blockIdx.x * 256 + threadIdx.x) * 8;
  float4 a = *reinterpret_cast<const float4*>(x + i);
  float4 b = *reinterpret_cast<const float4*>(x + i + 4);
  short8 o;
  o[0] = (short)f2b(a.x); o[1] = (short)f2b(a.y);
  o[2] = (short)f2b(a.z); o[3] = (short)f2b(a.w);
  o[4] = (short)f2b(b.x); o[5] = (short)f2b(b.y);
  o[6] = (short)f2b(b.z); o[7] = (short)f2b(b.w);
  *reinterpret_cast<short8*>(xb + i) = o;
}

// ---------- transpose+cast weights: W[k][n] f32 -> WT[n][k] bf16 ------------
__global__ __launch_bounds__(256) void k_transW(const float* __restrict__ Wq,
                                                const float* __restrict__ Wk,
                                                const float* __restrict__ Wv,
                                                const float* __restrict__ Wo,
                                                unsigned short* __restrict__ WcatT,
                                                unsigned short* __restrict__ WoT) {
  int wsel = blockIdx.z;
  const float* src = wsel == 0 ? Wq : wsel == 1 ? Wk : wsel == 2 ? Wv : Wo;
  unsigned short* dst = (wsel < 3) ? (WcatT + (size_t)wsel * 1024 * 1024) : WoT;
  int k0 = blockIdx.x * 64, n0 = blockIdx.y * 64;
  __shared__ float tile[64][65];
  int tr = threadIdx.x >> 6, tc = threadIdx.x & 63;
#pragma unroll
  for (int i = 0; i < 16; ++i) {
    int r = i * 4 + tr;
    tile[r][tc] = src[(size_t)(k0 + r) * 1024 + n0 + tc];
  }
  __syncthreads();
#pragma unroll
  for (int i = 0; i < 16; ++i) {
    int r = i * 4 + tr;
    dst[(size_t)(n0 + r) * 1024 + k0 + tc] = f2b(tile[tc][r]);
  }
}

// ---- pack adj*log2e (bf16 hi) + mask bit (lo) into AM[kt][h][g][q][8] ------
// For key k: kt=k>>6, kk=k&63, h=kk>>5, g=(kk>>3)&3, e=kk&7.
__global__ __launch_bounds__(256) void k_pack(const float* __restrict__ adj,
                                              const int* __restrict__ mask,
                                              unsigned int* __restrict__ AM) {
  const float L2E = 1.4426950408889634f;
  int i = (blockIdx.x * 256 + threadIdx.x) * 4;
  int q = i >> 10, c = i & 1023;
  float4 a = *reinterpret_cast<const float4*>(adj + i);
  int4 m = *reinterpret_cast<const int4*>(mask + i);
  int kt = c >> 6, h = (c >> 5) & 1, g = (c >> 3) & 3, e0 = c & 7;  // e0 in {0,4}
  unsigned W = (unsigned)((kt * 8 + h * 4 + g) * 8192 + q * 8 + e0);
  uint4 o;
  o.x = ((unsigned)f2b(a.x * L2E) << 16) | (m.x != 0 ? 1u : 0u);
  o.y = ((unsigned)f2b(a.y * L2E) << 16) | (m.y != 0 ? 1u : 0u);
  o.z = ((unsigned)f2b(a.z * L2E) << 16) | (m.z != 0 ? 1u : 0u);
  o.w = ((unsigned)f2b(a.w * L2E) << 16) | (m.w != 0 ? 1u : 0u);
  *reinterpret_cast<uint4*>(AM + W) = o;
}

// ---------------- m97-style bf16 GEMM: C = A(MxK) @ BT(NxK)^T + bias --------
template <int MODE>
__global__ __launch_bounds__(256) void k_gemm(
    const unsigned short* __restrict__ A, const unsigned short* __restrict__ BT,
    float* __restrict__ outF,
    unsigned short* __restrict__ oQ, unsigned short* __restrict__ oK,
    unsigned short* __restrict__ oV,
    const float* __restrict__ b0, const float* __restrict__ b1,
    const float* __restrict__ b2, int M, int N, int K) {
  __shared__ unsigned short As[128 * 32], Bs[128 * 32];
  const int tid = threadIdx.x;
  const int w = tid >> 6, l = tid & 63, l15 = l & 15, l4 = l >> 4;
  const int m0 = blockIdx.x * 128, n0 = blockIdx.y * 128;
  const int wm = (w >> 1) * 64, wn = (w & 1) * 64;
  f32x4 acc[4][4];
#pragma unroll
  for (int i = 0; i < 4; ++i)
#pragma unroll
    for (int j = 0; j < 4; ++j) acc[i][j] = f32x4{0.f, 0.f, 0.f, 0.f};

  const int nkt = K >> 5;
  for (int kt = 0; kt < nkt; ++kt) {
#pragma unroll
    for (int i = 0; i < 2; ++i) {
      int c = i * 256 + tid;
      gload_lds16(A + (size_t)(m0 + (c >> 2)) * K + kt * 32 + (c & 3) * 8,
                  (char*)As + c * 16);
      gload_lds16(BT + (size_t)(n0 + (c >> 2)) * K + kt * 32 + (c & 3) * 8,
                  (char*)Bs + c * 16);
    }
    __syncthreads();
    short8 af[4], bf[4];
#pragma unroll
    for (int i = 0; i < 4; ++i)
      af[i] = *reinterpret_cast<const short8*>(As + (wm + i * 16 + l15) * 32 + l4 * 8);
#pragma unroll
    for (int j = 0; j < 4; ++j)
      bf[j] = *reinterpret_cast<const short8*>(Bs + (wn + j * 16 + l15) * 32 + l4 * 8);
#pragma unroll
    for (int i = 0; i < 4; ++i)
#pragma unroll
      for (int j = 0; j < 4; ++j) acc[i][j] = mfma16(af[i], bf[j], acc[i][j]);
    __syncthreads();
  }
#pragma unroll
  for (int i = 0; i < 4; ++i)
#pragma unroll
    for (int j = 0; j < 4; ++j) {
      int gr0 = m0 + wm + i * 16 + l4 * 4;
      int gc = n0 + wn + j * 16 + l15;
      if (MODE == 0) {
        int mat = gc >> 10, nl = gc & 1023;
        const float* bp = mat == 0 ? b0 : mat == 1 ? b1 : b2;
        unsigned short* op = mat == 0 ? oQ : mat == 1 ? oK : oV;
        float bb = bp[nl];
#pragma unroll
        for (int r = 0; r < 4; ++r)
          op[(size_t)(gr0 + r) * 1024 + nl] = f2b(acc[i][j][r] + bb);
      } else {
        float bb = b0[gc];
#pragma unroll
        for (int r = 0; r < 4; ++r)
          outF[(size_t)(gr0 + r) * N + gc] = acc[i][j][r] + bb;
      }
    }
}

// ---------------- dual-softmax flash attention (no-max, reg-P) --------------
// grid (64 groups, 16 q-tiles), 256 thr (4 waves), wave owns 16 q rows.
// Swapped QK^T; P stays in registers (cvt_pk pairs == PV A-frag order).
__global__ __launch_bounds__(256, 4) void k_attn(
    const unsigned short* __restrict__ Qb, const unsigned short* __restrict__ Kb,
    const unsigned short* __restrict__ Vb, const unsigned int* __restrict__ AM,
    float* __restrict__ Xg, float* __restrict__ Xl) {
  const int g = blockIdx.x;
  const int q0 = blockIdx.y * 64;
  const int tid = threadIdx.x;
  const int w = tid >> 6, l = tid & 63, l15 = l & 15, l4 = l >> 4;

  __shared__ unsigned short Kt[2][2][64][32];  // [buf][dk][key][slot] XOR'd
  __shared__ unsigned short Vs[2][4][64][16];  // [buf][db][k][d&15] subtiled

  const size_t gbase = (size_t)g << 16;
  const unsigned short* Qg = Qb + gbase;
  const unsigned short* Kg = Kb + gbase;
  const unsigned short* Vg = Vb + gbase;

  // Q frags (B-operand of swapped QK^T): lane holds Q[q=l15][d=l4*8+j].
  short8 qf[2];
  {
    const unsigned short* qp = Qg + (size_t)(q0 + w * 16 + l15) * 64 + l4 * 8;
    qf[0] = *reinterpret_cast<const short8*>(qp);
    qf[1] = *reinterpret_cast<const short8*>(qp + 32);
  }
  short8 onesf;
#pragma unroll
  for (int j = 0; j < 8; ++j) onesf[j] = (short)0x3F80;  // bf16 1.0

  f32x4 accg[4], accl[4];
#pragma unroll
  for (int d = 0; d < 4; ++d) {
    accg[d] = f32x4{0.f, 0.f, 0.f, 0.f};
    accl[d] = f32x4{0.f, 0.f, 0.f, 0.f};
  }
  f32x4 sumg = f32x4{0.f, 0.f, 0.f, 0.f}, suml = f32x4{0.f, 0.f, 0.f, 0.f};

  const float NF2 = 0.04508422002778f;  // log2e / 32
  const int q_abs = q0 + w * 16 + l15;  // this lane's q row (softmax side)
  const int qrow = q0 + w * 16 + l4 * 4;  // +r (PV output side)

  // K-frag byte offsets within Kt[b][dk]: A-row rho=l15 -> key
  // key = 8*(rho>>2)+(rho&3)+4*(cb&1)+32*(cb>>1); slot = l4 ^ sigma(key).
  int koff[4];
#pragma unroll
  for (int cb = 0; cb < 4; ++cb) {
    int key = 8 * (l15 >> 2) + (l15 & 3) + 4 * (cb & 1) + 32 * (cb >> 1);
    int sl = l4 ^ (((key >> 1) ^ (key >> 3)) & 3);
    koff[cb] = key * 64 + sl * 16;
  }
  const unsigned ktb = ldsoff(&Kt[0][0][0][0]);
  const unsigned vsb = ldsoff(&Vs[0][0][0][0]) + (unsigned)(l4 * 256 + l15 * 8);
  const unsigned* AMq = AM + (size_t)q_abs * 8;

  auto stage = [&](int b, int kk0) {
#pragma unroll
    for (int i = 0; i < 2; ++i) {
      int c = i * 256 + tid;
      int dk = c >> 8, key = (c >> 2) & 63, slot = c & 3;
      int ls = slot ^ (((key >> 1) ^ (key >> 3)) & 3);
      gload_lds16(Kg + (size_t)(kk0 + key) * 64 + dk * 32 + ls * 8,
                  (char*)Kt + b * 8192 + c * 16);
    }
#pragma unroll
    for (int i = 0; i < 2; ++i) {
      int c = i * 256 + tid;
      int db = c >> 7, k = (c >> 1) & 63, h = c & 1;
      gload_lds16(Vg + (size_t)(kk0 + k) * 64 + db * 16 + h * 8,
                  (char*)Vs + b * 8192 + c * 16);
    }
  };

  stage(0, 0);
  __syncthreads();

#pragma unroll 2
  for (int kt = 0; kt < 16; ++kt) {
    const int b = kt & 1;
    if (kt < 15) stage(b ^ 1, (kt + 1) * 64);  // async prefetch next tile

    // --- AM: 4 coalesced uint4 (this lane's q row; keys 8*l4+e (+32h)) -----
    union { uint4 v; unsigned u[4]; } amc[4];
    {
      const unsigned* p0 = AMq + (size_t)(kt * 8 + l4) * 8192;
      const unsigned* p1 = AMq + (size_t)(kt * 8 + 4 + l4) * 8192;
      amc[0].v = *reinterpret_cast<const uint4*>(p0);      // cb0: e=r
      amc[1].v = *reinterpret_cast<const uint4*>(p0 + 4);  // cb1: e=4+r
      amc[2].v = *reinterpret_cast<const uint4*>(p1);      // cb2
      amc[3].v = *reinterpret_cast<const uint4*>(p1 + 4);  // cb3
    }

    // --- swapped S^T = K Q : accs[cb][r] = S[key=8*l4+r+off(cb)][q=l15] ----
    f32x4 accs[4];
#pragma unroll
    for (int cb = 0; cb < 4; ++cb) {
      accs[cb] = f32x4{0.f, 0.f, 0.f, 0.f};
#pragma unroll
      for (int dk = 0; dk < 2; ++dk) {
        short8 kf = *reinterpret_cast<const short8*>(
            (const char*)Kt + b * 8192 + dk * 4096 + koff[cb]);
        accs[cb] = mfma16(kf, qf[dk], accs[cb]);
      }
    }

    // --- issue V tr_reads for ks=0 early (latency under softmax VALU) ------
    const unsigned vb = vsb + (unsigned)(b << 13);
    union { short8 s8; i32x2 d[2]; } vf[4];
#pragma unroll
    for (int db = 0; db < 4; ++db) {
      vf[db].d[0] = dstr<0>(vb + db * 2048);
      vf[db].d[1] = dstr<128>(vb + db * 2048);
    }

    // --- no-max dual softmax, P packed straight into PV A-frag order -------
    unsigned pgq[8], plq[8];  // pair cb*2+c = keys (8*l4+4*(cb&1)+32*(cb>>1)+2c, +1)
#pragma unroll
    for (int cb = 0; cb < 4; ++cb) {
      unsigned a0 = amc[cb].u[0], a1 = amc[cb].u[1];
      unsigned a2 = amc[cb].u[2], a3 = amc[cb].u[3];
      float e0 = exp2h(fmaf(accs[cb][0], NF2, __uint_as_float(a0 & 0xffff0000u)));
      float e1 = exp2h(fmaf(accs[cb][1], NF2, __uint_as_float(a1 & 0xffff0000u)));
      float e2 = exp2h(fmaf(accs[cb][2], NF2, __uint_as_float(a2 & 0xffff0000u)));
      float e3 = exp2h(fmaf(accs[cb][3], NF2, __uint_as_float(a3 & 0xffff0000u)));
      float z0 = (a0 & 1u) ? e0 : 0.f;
      float z1 = (a1 & 1u) ? e1 : 0.f;
      float z2 = (a2 & 1u) ? e2 : 0.f;
      float z3 = (a3 & 1u) ? e3 : 0.f;
      pgq[cb * 2]     = cvtpk(e0, e1);
      pgq[cb * 2 + 1] = cvtpk(e2, e3);
      plq[cb * 2]     = cvtpk(z0, z1);
      plq[cb * 2 + 1] = cvtpk(z2, z3);
    }
    union { short8 s8; unsigned u[4]; } pg0, pl0, pg1, pl1;
#pragma unroll
    for (int v = 0; v < 4; ++v) {
      pg0.u[v] = pgq[v];     pl0.u[v] = plq[v];      // ks=0: cb 0,1
      pg1.u[v] = pgq[4 + v]; pl1.u[v] = plq[4 + v];  // ks=1: cb 2,3
    }

    // --- PV ks=0 -----------------------------------------------------------
    asm volatile("s_waitcnt lgkmcnt(0)" ::: "memory");
    __builtin_amdgcn_sched_barrier(0);
#pragma unroll
    for (int db = 0; db < 4; ++db) {
      accg[db] = mfma16(pg0.s8, vf[db].s8, accg[db]);
      accl[db] = mfma16(pl0.s8, vf[db].s8, accl[db]);
    }
    sumg = mfma16(pg0.s8, onesf, sumg);
    suml = mfma16(pl0.s8, onesf, suml);

    // --- V tr_reads ks=1, then PV ks=1 -------------------------------------
#pragma unroll
    for (int db = 0; db < 4; ++db) {
      vf[db].d[0] = dstr<1024>(vb + db * 2048);
      vf[db].d[1] = dstr<1024 + 128>(vb + db * 2048);
    }
    asm volatile("s_waitcnt lgkmcnt(0)" ::: "memory");
    __builtin_amdgcn_sched_barrier(0);
#pragma unroll
    for (int db = 0; db < 4; ++db) {
      accg[db] = mfma16(pg1.s8, vf[db].s8, accg[db]);
      accl[db] = mfma16(pl1.s8, vf[db].s8, accl[db]);
    }
    sumg = mfma16(pg1.s8, onesf, sumg);
    suml = mfma16(pl1.s8, onesf, suml);

    __syncthreads();
  }

  // --- epilogue: O = acc / rowsum (row q = qrow + r, col d = db*16+l15) ----
#pragma unroll
  for (int r = 0; r < 4; ++r) {
    float ig = 1.f / sumg[r];
    float il = suml[r] > 0.f ? 1.f / suml[r] : 0.f;
#pragma unroll
    for (int db = 0; db < 4; ++db) {
      size_t o = gbase + (size_t)(qrow + r) * 64 + db * 16 + l15;
      Xg[o] = accg[db][r] * ig;
      Xl[o] = accl[db][r] * il;
    }
  }
}

// ------- combine: gate, signed-sqrt, row L2-norm, cast bf16 -----------------
__global__ __launch_bounds__(256) void k_combine(const float* __restrict__ Xg,
                                                 const float* __restrict__ Xl,
                                                 const float* __restrict__ alphap,
                                                 unsigned short* __restrict__ xob) {
  int row = blockIdx.x, tid = threadIdx.x;
  int w = tid >> 6, l = tid & 63;
  size_t base = (size_t)row * 1024 + tid * 4;
  float a = 1.f / (1.f + __expf(-alphap[0]));
  float4 gx = *reinterpret_cast<const float4*>(Xg + base);
  float4 lx = *reinterpret_cast<const float4*>(Xl + base);
  float v[4];
  {
    float t0 = a * gx.x + (1.f - a) * lx.x;
    float t1 = a * gx.y + (1.f - a) * lx.y;
    float t2 = a * gx.z + (1.f - a) * lx.z;
    float t3 = a * gx.w + (1.f - a) * lx.w;
    v[0] = t0 >= 0.f ? sqrtf(t0) : -sqrtf(-t0);
    v[1] = t1 >= 0.f ? sqrtf(t1) : -sqrtf(-t1);
    v[2] = t2 >= 0.f ? sqrtf(t2) : -sqrtf(-t2);
    v[3] = t3 >= 0.f ? sqrtf(t3) : -sqrtf(-t3);
  }
  float ss = v[0] * v[0] + v[1] * v[1] + v[2] * v[2] + v[3] * v[3];
#pragma unroll
  for (int off = 1; off < 64; off <<= 1) ss += __shfl_xor(ss, off);
  __shared__ float wsum[4];
  if (l == 0) wsum[w] = ss;
  __syncthreads();
  float tot = wsum[0] + wsum[1] + wsum[2] + wsum[3];
  float scale = 1.f / fmaxf(sqrtf(tot), 1e-12f);
  ushort4 o;
  o.x = f2b(v[0] * scale); o.y = f2b(v[1] * scale);
  o.z = f2b(v[2] * scale); o.w = f2b(v[3] * scale);
  *reinterpret_cast<ushort4*>(xob + base) = o;
}

// ---------------------------------------------------------------------------
extern "C" void kernel_launch(void* const* d_in, const int* in_sizes, int n_in,
                              void* d_out, int out_size, void* d_ws, size_t ws_size,
                              hipStream_t stream) {
  const float* x     = (const float*)d_in[0];
  const int*   mask  = (const int*)d_in[1];
  const float* adj   = (const float*)d_in[2];
  const float* Wq    = (const float*)d_in[3];
  const float* bq    = (const float*)d_in[4];
  const float* Wk    = (const float*)d_in[5];
  const float* bk    = (const float*)d_in[6];
  const float* Wv    = (const float*)d_in[7];
  const float* bv    = (const float*)d_in[8];
  const float* Wo    = (const float*)d_in[9];
  const float* bo    = (const float*)d_in[10];
  const float* alpha = (const float*)d_in[11];
  float* out = (float*)d_out;
  char* ws = (char*)d_ws;

  unsigned short* xb    = (unsigned short*)(ws + 0);          //  8 MB
  unsigned short* WcatT = (unsigned short*)(ws + 8388608);    //  6 MB
  unsigned short* WoT   = (unsigned short*)(ws + 14680064);   //  2 MB
  unsigned short* Qb    = (unsigned short*)(ws + 16777216);   //  8 MB
  unsigned short* Kb    = (unsigned short*)(ws + 25165824);   //  8 MB
  unsigned short* Vb    = (unsigned short*)(ws + 33554432);   //  8 MB
  float*          Xg    = (float*)(ws + 41943040);            // 16 MB
  float*          Xl    = (float*)(ws + 58720256);            // 16 MB
  unsigned short* xob   = (unsigned short*)(ws + 75497472);   //  8 MB
  unsigned int*   AM    = (unsigned int*)(ws + 83886080);     //  4 MB

  k_cast_x<<<2048, 256, 0, stream>>>(x, xb);
  k_transW<<<dim3(16, 16, 4), 256, 0, stream>>>(Wq, Wk, Wv, Wo, WcatT, WoT);
  k_pack<<<1024, 256, 0, stream>>>(adj, mask, AM);
  k_gemm<0><<<dim3(32, 24), 256, 0, stream>>>(xb, WcatT, nullptr, Qb, Kb, Vb,
                                              bq, bk, bv, 4096, 3072, 1024);
  k_attn<<<dim3(64, 16), 256, 0, stream>>>(Qb, Kb, Vb, AM, Xg, Xl);
  k_combine<<<4096, 256, 0, stream>>>(Xg, Xl, alpha, xob);
  k_gemm<1><<<dim3(32, 8), 256, 0, stream>>>(xob, WoT, out, nullptr, nullptr,
                                             nullptr, bo, bo, bo, 4096, 1024, 1024);
}

// Round 11
// 222.818 us; speedup vs baseline: 1.3646x; 1.0345x over previous
//
#include <hip/hip_runtime.h>
#include <hip/hip_bf16.h>

// ---------------------------------------------------------------------------
// Fused dual-attention block (TCA_309237645935) for gfx950.  Round 11
// (identical to R8/R9/R10; all three were GPU-acquisition infra failures).
//
//  - k_gemm: T3-minimum 2-phase (double-buffered LDS, stage(next) issued
//    BEFORE frag-read/MFMA of current, ONE barrier per K-tile).
//  - k_attn: sigmoid gate fused into epilogue -> single f32 Xc buffer
//    (-16MB write); s_setprio(1) around MFMA clusters (T5).
//  - k_combine: reads Xc only (-16MB read).
// ---------------------------------------------------------------------------

typedef __attribute__((ext_vector_type(8))) short short8;
typedef __attribute__((ext_vector_type(4))) float f32x4;
typedef __attribute__((ext_vector_type(2))) int i32x2;

__device__ __forceinline__ f32x4 mfma16(short8 a, short8 b, f32x4 c) {
  return __builtin_amdgcn_mfma_f32_16x16x32_bf16(a, b, c, 0, 0, 0);
}

__device__ __forceinline__ unsigned short f2b(float f) {
  __hip_bfloat16 h = __float2bfloat16(f);
  return *reinterpret_cast<unsigned short*>(&h);
}

__device__ __forceinline__ unsigned cvtpk(float lo, float hi) {
  unsigned r;
  asm("v_cvt_pk_bf16_f32 %0, %1, %2" : "=v"(r) : "v"(lo), "v"(hi));
  return r;
}

__device__ __forceinline__ float exp2h(float x) {
  float r;
  asm("v_exp_f32 %0, %1" : "=v"(r) : "v"(x));
  return r;
}

// LDS byte offset of a __shared__ object (addrspace(3) pointers are 32-bit).
__device__ __forceinline__ unsigned ldsoff(const void* p) {
  return (unsigned)(size_t)(const __attribute__((address_space(3))) char*)p;
}

// ds_read_b64_tr_b16: A' = addr+OFF; lane reads column (A'>>3)&15 of the
// 4x16 bf16 tile at A'&~127, elem j at +32B.  (Verified R5.)
template <int OFF>
__device__ __forceinline__ i32x2 dstr(unsigned addr) {
  i32x2 d;
  asm volatile("ds_read_b64_tr_b16 %0, %1 offset:%c2"
               : "=v"(d) : "v"(addr), "i"(OFF) : "memory");
  return d;
}

__device__ __forceinline__ void gload_lds16(const void* g, void* l) {
  __builtin_amdgcn_global_load_lds(
      (const __attribute__((address_space(1))) void*)g,
      (__attribute__((address_space(3))) void*)l, 16, 0, 0);
}

// ---------------- cast x (f32 -> bf16), 8 elems/thread ----------------------
__global__ __launch_bounds__(256) void k_cast_x(const float* __restrict__ x,
                                                unsigned short* __restrict__ xb) {
  int i = (blockIdx.x * 256 + threadIdx.x) * 8;
  float4 a = *reinterpret_cast<const float4*>(x + i);
  float4 b = *reinterpret_cast<const float4*>(x + i + 4);
  short8 o;
  o[0] = (short)f2b(a.x); o[1] = (short)f2b(a.y);
  o[2] = (short)f2b(a.z); o[3] = (short)f2b(a.w);
  o[4] = (short)f2b(b.x); o[5] = (short)f2b(b.y);
  o[6] = (short)f2b(b.z); o[7] = (short)f2b(b.w);
  *reinterpret_cast<short8*>(xb + i) = o;
}

// ---------- transpose+cast weights: W[k][n] f32 -> WT[n][k] bf16 ------------
__global__ __launch_bounds__(256) void k_transW(const float* __restrict__ Wq,
                                                const float* __restrict__ Wk,
                                                const float* __restrict__ Wv,
                                                const float* __restrict__ Wo,
                                                unsigned short* __restrict__ WcatT,
                                                unsigned short* __restrict__ WoT) {
  int wsel = blockIdx.z;
  const float* src = wsel == 0 ? Wq : wsel == 1 ? Wk : wsel == 2 ? Wv : Wo;
  unsigned short* dst = (wsel < 3) ? (WcatT + (size_t)wsel * 1024 * 1024) : WoT;
  int k0 = blockIdx.x * 64, n0 = blockIdx.y * 64;
  __shared__ float tile[64][65];
  int tr = threadIdx.x >> 6, tc = threadIdx.x & 63;
#pragma unroll
  for (int i = 0; i < 16; ++i) {
    int r = i * 4 + tr;
    tile[r][tc] = src[(size_t)(k0 + r) * 1024 + n0 + tc];
  }
  __syncthreads();
#pragma unroll
  for (int i = 0; i < 16; ++i) {
    int r = i * 4 + tr;
    dst[(size_t)(n0 + r) * 1024 + k0 + tc] = f2b(tile[tc][r]);
  }
}

// ---- pack adj*log2e (bf16 hi) + mask bit (lo) into AM[kt][h][g][q][8] ------
__global__ __launch_bounds__(256) void k_pack(const float* __restrict__ adj,
                                              const int* __restrict__ mask,
                                              unsigned int* __restrict__ AM) {
  const float L2E = 1.4426950408889634f;
  int i = (blockIdx.x * 256 + threadIdx.x) * 4;
  int q = i >> 10, c = i & 1023;
  float4 a = *reinterpret_cast<const float4*>(adj + i);
  int4 m = *reinterpret_cast<const int4*>(mask + i);
  int kt = c >> 6, h = (c >> 5) & 1, g = (c >> 3) & 3, e0 = c & 7;  // e0 in {0,4}
  unsigned W = (unsigned)((kt * 8 + h * 4 + g) * 8192 + q * 8 + e0);
  uint4 o;
  o.x = ((unsigned)f2b(a.x * L2E) << 16) | (m.x != 0 ? 1u : 0u);
  o.y = ((unsigned)f2b(a.y * L2E) << 16) | (m.y != 0 ? 1u : 0u);
  o.z = ((unsigned)f2b(a.z * L2E) << 16) | (m.z != 0 ? 1u : 0u);
  o.w = ((unsigned)f2b(a.w * L2E) << 16) | (m.w != 0 ? 1u : 0u);
  *reinterpret_cast<uint4*>(AM + W) = o;
}

// -------- 2-phase bf16 GEMM: C = A(MxK) @ BT(NxK)^T + bias ------------------
// Double-buffered LDS; stage(next) issued before compute(cur); 1 barrier/tile.
template <int MODE>
__global__ __launch_bounds__(256) void k_gemm(
    const unsigned short* __restrict__ A, const unsigned short* __restrict__ BT,
    float* __restrict__ outF,
    unsigned short* __restrict__ oQ, unsigned short* __restrict__ oK,
    unsigned short* __restrict__ oV,
    const float* __restrict__ b0, const float* __restrict__ b1,
    const float* __restrict__ b2, int M, int N, int K) {
  __shared__ unsigned short As[2][128 * 32], Bs[2][128 * 32];
  const int tid = threadIdx.x;
  const int w = tid >> 6, l = tid & 63, l15 = l & 15, l4 = l >> 4;
  const int m0 = blockIdx.x * 128, n0 = blockIdx.y * 128;
  const int wm = (w >> 1) * 64, wn = (w & 1) * 64;
  f32x4 acc[4][4];
#pragma unroll
  for (int i = 0; i < 4; ++i)
#pragma unroll
    for (int j = 0; j < 4; ++j) acc[i][j] = f32x4{0.f, 0.f, 0.f, 0.f};

  auto stage = [&](int b, int kt) {
#pragma unroll
    for (int i = 0; i < 2; ++i) {
      int c = i * 256 + tid;
      gload_lds16(A + (size_t)(m0 + (c >> 2)) * K + kt * 32 + (c & 3) * 8,
                  (char*)As[b] + c * 16);
      gload_lds16(BT + (size_t)(n0 + (c >> 2)) * K + kt * 32 + (c & 3) * 8,
                  (char*)Bs[b] + c * 16);
    }
  };

  const int nkt = K >> 5;
  stage(0, 0);
  __syncthreads();

  for (int kt = 0; kt < nkt; ++kt) {
    const int b = kt & 1;
    if (kt + 1 < nkt) stage(b ^ 1, kt + 1);  // prefetch overlaps compute
    short8 af[4], bf[4];
#pragma unroll
    for (int i = 0; i < 4; ++i)
      af[i] = *reinterpret_cast<const short8*>(As[b] + (wm + i * 16 + l15) * 32 + l4 * 8);
#pragma unroll
    for (int j = 0; j < 4; ++j)
      bf[j] = *reinterpret_cast<const short8*>(Bs[b] + (wn + j * 16 + l15) * 32 + l4 * 8);
#pragma unroll
    for (int i = 0; i < 4; ++i)
#pragma unroll
      for (int j = 0; j < 4; ++j) acc[i][j] = mfma16(af[i], bf[j], acc[i][j]);
    __syncthreads();  // drains prefetch (vmcnt) + LDS reads, then barrier
  }
#pragma unroll
  for (int i = 0; i < 4; ++i)
#pragma unroll
    for (int j = 0; j < 4; ++j) {
      int gr0 = m0 + wm + i * 16 + l4 * 4;
      int gc = n0 + wn + j * 16 + l15;
      if (MODE == 0) {
        int mat = gc >> 10, nl = gc & 1023;
        const float* bp = mat == 0 ? b0 : mat == 1 ? b1 : b2;
        unsigned short* op = mat == 0 ? oQ : mat == 1 ? oK : oV;
        float bb = bp[nl];
#pragma unroll
        for (int r = 0; r < 4; ++r)
          op[(size_t)(gr0 + r) * 1024 + nl] = f2b(acc[i][j][r] + bb);
      } else {
        float bb = b0[gc];
#pragma unroll
        for (int r = 0; r < 4; ++r)
          outF[(size_t)(gr0 + r) * N + gc] = acc[i][j][r] + bb;
      }
    }
}

// ---------------- dual-softmax flash attention (no-max, reg-P) --------------
// grid (64 groups, 16 q-tiles), 256 thr (4 waves), wave owns 16 q rows.
// Swapped QK^T; P in registers; gate fused in epilogue -> one Xc buffer.
__global__ __launch_bounds__(256, 4) void k_attn(
    const unsigned short* __restrict__ Qb, const unsigned short* __restrict__ Kb,
    const unsigned short* __restrict__ Vb, const unsigned int* __restrict__ AM,
    const float* __restrict__ alphap, float* __restrict__ Xc) {
  const int g = blockIdx.x;
  const int q0 = blockIdx.y * 64;
  const int tid = threadIdx.x;
  const int w = tid >> 6, l = tid & 63, l15 = l & 15, l4 = l >> 4;

  __shared__ unsigned short Kt[2][2][64][32];  // [buf][dk][key][slot] XOR'd
  __shared__ unsigned short Vs[2][4][64][16];  // [buf][db][k][d&15] subtiled

  const size_t gbase = (size_t)g << 16;
  const unsigned short* Qg = Qb + gbase;
  const unsigned short* Kg = Kb + gbase;
  const unsigned short* Vg = Vb + gbase;

  short8 qf[2];
  {
    const unsigned short* qp = Qg + (size_t)(q0 + w * 16 + l15) * 64 + l4 * 8;
    qf[0] = *reinterpret_cast<const short8*>(qp);
    qf[1] = *reinterpret_cast<const short8*>(qp + 32);
  }
  short8 onesf;
#pragma unroll
  for (int j = 0; j < 8; ++j) onesf[j] = (short)0x3F80;  // bf16 1.0

  f32x4 accg[4], accl[4];
#pragma unroll
  for (int d = 0; d < 4; ++d) {
    accg[d] = f32x4{0.f, 0.f, 0.f, 0.f};
    accl[d] = f32x4{0.f, 0.f, 0.f, 0.f};
  }
  f32x4 sumg = f32x4{0.f, 0.f, 0.f, 0.f}, suml = f32x4{0.f, 0.f, 0.f, 0.f};

  const float NF2 = 0.04508422002778f;  // log2e / 32
  const int q_abs = q0 + w * 16 + l15;
  const int qrow = q0 + w * 16 + l4 * 4;  // +r (PV output side)

  int koff[4];
#pragma unroll
  for (int cb = 0; cb < 4; ++cb) {
    int key = 8 * (l15 >> 2) + (l15 & 3) + 4 * (cb & 1) + 32 * (cb >> 1);
    int sl = l4 ^ (((key >> 1) ^ (key >> 3)) & 3);
    koff[cb] = key * 64 + sl * 16;
  }
  const unsigned vsb = ldsoff(&Vs[0][0][0][0]) + (unsigned)(l4 * 256 + l15 * 8);
  const unsigned* AMq = AM + (size_t)q_abs * 8;

  auto stage = [&](int b, int kk0) {
#pragma unroll
    for (int i = 0; i < 2; ++i) {
      int c = i * 256 + tid;
      int dk = c >> 8, key = (c >> 2) & 63, slot = c & 3;
      int ls = slot ^ (((key >> 1) ^ (key >> 3)) & 3);
      gload_lds16(Kg + (size_t)(kk0 + key) * 64 + dk * 32 + ls * 8,
                  (char*)Kt + b * 8192 + c * 16);
    }
#pragma unroll
    for (int i = 0; i < 2; ++i) {
      int c = i * 256 + tid;
      int db = c >> 7, k = (c >> 1) & 63, h = c & 1;
      gload_lds16(Vg + (size_t)(kk0 + k) * 64 + db * 16 + h * 8,
                  (char*)Vs + b * 8192 + c * 16);
    }
  };

  stage(0, 0);
  __syncthreads();

#pragma unroll 2
  for (int kt = 0; kt < 16; ++kt) {
    const int b = kt & 1;
    if (kt < 15) stage(b ^ 1, (kt + 1) * 64);  // async prefetch next tile

    union { uint4 v; unsigned u[4]; } amc[4];
    {
      const unsigned* p0 = AMq + (size_t)(kt * 8 + l4) * 8192;
      const unsigned* p1 = AMq + (size_t)(kt * 8 + 4 + l4) * 8192;
      amc[0].v = *reinterpret_cast<const uint4*>(p0);
      amc[1].v = *reinterpret_cast<const uint4*>(p0 + 4);
      amc[2].v = *reinterpret_cast<const uint4*>(p1);
      amc[3].v = *reinterpret_cast<const uint4*>(p1 + 4);
    }

    // --- swapped S^T = K Q ------------------------------------------------
    f32x4 accs[4];
    __builtin_amdgcn_s_setprio(1);
#pragma unroll
    for (int cb = 0; cb < 4; ++cb) {
      accs[cb] = f32x4{0.f, 0.f, 0.f, 0.f};
#pragma unroll
      for (int dk = 0; dk < 2; ++dk) {
        short8 kf = *reinterpret_cast<const short8*>(
            (const char*)Kt + b * 8192 + dk * 4096 + koff[cb]);
        accs[cb] = mfma16(kf, qf[dk], accs[cb]);
      }
    }
    __builtin_amdgcn_s_setprio(0);

    // --- issue V tr_reads for ks=0 early ----------------------------------
    const unsigned vb = vsb + (unsigned)(b << 13);
    union { short8 s8; i32x2 d[2]; } vf[4];
#pragma unroll
    for (int db = 0; db < 4; ++db) {
      vf[db].d[0] = dstr<0>(vb + db * 2048);
      vf[db].d[1] = dstr<128>(vb + db * 2048);
    }

    // --- no-max dual softmax, P packed in PV A-frag order ------------------
    unsigned pgq[8], plq[8];
#pragma unroll
    for (int cb = 0; cb < 4; ++cb) {
      unsigned a0 = amc[cb].u[0], a1 = amc[cb].u[1];
      unsigned a2 = amc[cb].u[2], a3 = amc[cb].u[3];
      float e0 = exp2h(fmaf(accs[cb][0], NF2, __uint_as_float(a0 & 0xffff0000u)));
      float e1 = exp2h(fmaf(accs[cb][1], NF2, __uint_as_float(a1 & 0xffff0000u)));
      float e2 = exp2h(fmaf(accs[cb][2], NF2, __uint_as_float(a2 & 0xffff0000u)));
      float e3 = exp2h(fmaf(accs[cb][3], NF2, __uint_as_float(a3 & 0xffff0000u)));
      float z0 = (a0 & 1u) ? e0 : 0.f;
      float z1 = (a1 & 1u) ? e1 : 0.f;
      float z2 = (a2 & 1u) ? e2 : 0.f;
      float z3 = (a3 & 1u) ? e3 : 0.f;
      pgq[cb * 2]     = cvtpk(e0, e1);
      pgq[cb * 2 + 1] = cvtpk(e2, e3);
      plq[cb * 2]     = cvtpk(z0, z1);
      plq[cb * 2 + 1] = cvtpk(z2, z3);
    }
    union { short8 s8; unsigned u[4]; } pg0, pl0, pg1, pl1;
#pragma unroll
    for (int v = 0; v < 4; ++v) {
      pg0.u[v] = pgq[v];     pl0.u[v] = plq[v];
      pg1.u[v] = pgq[4 + v]; pl1.u[v] = plq[4 + v];
    }

    // --- PV ks=0 -----------------------------------------------------------
    asm volatile("s_waitcnt lgkmcnt(0)" ::: "memory");
    __builtin_amdgcn_sched_barrier(0);
    __builtin_amdgcn_s_setprio(1);
#pragma unroll
    for (int db = 0; db < 4; ++db) {
      accg[db] = mfma16(pg0.s8, vf[db].s8, accg[db]);
      accl[db] = mfma16(pl0.s8, vf[db].s8, accl[db]);
    }
    sumg = mfma16(pg0.s8, onesf, sumg);
    suml = mfma16(pl0.s8, onesf, suml);
    __builtin_amdgcn_s_setprio(0);

    // --- V tr_reads ks=1, then PV ks=1 -------------------------------------
#pragma unroll
    for (int db = 0; db < 4; ++db) {
      vf[db].d[0] = dstr<1024>(vb + db * 2048);
      vf[db].d[1] = dstr<1024 + 128>(vb + db * 2048);
    }
    asm volatile("s_waitcnt lgkmcnt(0)" ::: "memory");
    __builtin_amdgcn_sched_barrier(0);
    __builtin_amdgcn_s_setprio(1);
#pragma unroll
    for (int db = 0; db < 4; ++db) {
      accg[db] = mfma16(pg1.s8, vf[db].s8, accg[db]);
      accl[db] = mfma16(pl1.s8, vf[db].s8, accl[db]);
    }
    sumg = mfma16(pg1.s8, onesf, sumg);
    suml = mfma16(pl1.s8, onesf, suml);
    __builtin_amdgcn_s_setprio(0);

    __syncthreads();
  }

  // --- epilogue: Xc = a*(accg/sumg) + (1-a)*(accl/suml), fused gate --------
  const float a = 1.f / (1.f + __expf(-alphap[0]));
#pragma unroll
  for (int r = 0; r < 4; ++r) {
    float ig = a / sumg[r];
    float il = suml[r] > 0.f ? (1.f - a) / suml[r] : 0.f;
#pragma unroll
    for (int db = 0; db < 4; ++db) {
      size_t o = gbase + (size_t)(qrow + r) * 64 + db * 16 + l15;
      Xc[o] = accg[db][r] * ig + accl[db][r] * il;
    }
  }
}

// ------- combine: signed-sqrt, row L2-norm, cast bf16 -----------------------
__global__ __launch_bounds__(256) void k_combine(const float* __restrict__ Xc,
                                                 unsigned short* __restrict__ xob) {
  int row = blockIdx.x, tid = threadIdx.x;
  int w = tid >> 6, l = tid & 63;
  size_t base = (size_t)row * 1024 + tid * 4;
  float4 cx = *reinterpret_cast<const float4*>(Xc + base);
  float v[4];
  v[0] = cx.x >= 0.f ? sqrtf(cx.x) : -sqrtf(-cx.x);
  v[1] = cx.y >= 0.f ? sqrtf(cx.y) : -sqrtf(-cx.y);
  v[2] = cx.z >= 0.f ? sqrtf(cx.z) : -sqrtf(-cx.z);
  v[3] = cx.w >= 0.f ? sqrtf(cx.w) : -sqrtf(-cx.w);
  float ss = v[0] * v[0] + v[1] * v[1] + v[2] * v[2] + v[3] * v[3];
#pragma unroll
  for (int off = 1; off < 64; off <<= 1) ss += __shfl_xor(ss, off);
  __shared__ float wsum[4];
  if (l == 0) wsum[w] = ss;
  __syncthreads();
  float tot = wsum[0] + wsum[1] + wsum[2] + wsum[3];
  float scale = 1.f / fmaxf(sqrtf(tot), 1e-12f);
  ushort4 o;
  o.x = f2b(v[0] * scale); o.y = f2b(v[1] * scale);
  o.z = f2b(v[2] * scale); o.w = f2b(v[3] * scale);
  *reinterpret_cast<ushort4*>(xob + base) = o;
}

// ---------------------------------------------------------------------------
extern "C" void kernel_launch(void* const* d_in, const int* in_sizes, int n_in,
                              void* d_out, int out_size, void* d_ws, size_t ws_size,
                              hipStream_t stream) {
  const float* x     = (const float*)d_in[0];
  const int*   mask  = (const int*)d_in[1];
  const float* adj   = (const float*)d_in[2];
  const float* Wq    = (const float*)d_in[3];
  const float* bq    = (const float*)d_in[4];
  const float* Wk    = (const float*)d_in[5];
  const float* bk    = (const float*)d_in[6];
  const float* Wv    = (const float*)d_in[7];
  const float* bv    = (const float*)d_in[8];
  const float* Wo    = (const float*)d_in[9];
  const float* bo    = (const float*)d_in[10];
  const float* alpha = (const float*)d_in[11];
  float* out = (float*)d_out;
  char* ws = (char*)d_ws;

  unsigned short* xb    = (unsigned short*)(ws + 0);          //  8 MB
  unsigned short* WcatT = (unsigned short*)(ws + 8388608);    //  6 MB
  unsigned short* WoT   = (unsigned short*)(ws + 14680064);   //  2 MB
  unsigned short* Qb    = (unsigned short*)(ws + 16777216);   //  8 MB
  unsigned short* Kb    = (unsigned short*)(ws + 25165824);   //  8 MB
  unsigned short* Vb    = (unsigned short*)(ws + 33554432);   //  8 MB
  float*          Xc    = (float*)(ws + 41943040);            // 16 MB
  unsigned short* xob   = (unsigned short*)(ws + 58720256);   //  8 MB
  unsigned int*   AM    = (unsigned int*)(ws + 67108864);     //  4 MB

  k_cast_x<<<2048, 256, 0, stream>>>(x, xb);
  k_transW<<<dim3(16, 16, 4), 256, 0, stream>>>(Wq, Wk, Wv, Wo, WcatT, WoT);
  k_pack<<<1024, 256, 0, stream>>>(adj, mask, AM);
  k_gemm<0><<<dim3(32, 24), 256, 0, stream>>>(xb, WcatT, nullptr, Qb, Kb, Vb,
                                              bq, bk, bv, 4096, 3072, 1024);
  k_attn<<<dim3(64, 16), 256, 0, stream>>>(Qb, Kb, Vb, AM, alpha, Xc);
  k_combine<<<4096, 256, 0, stream>>>(Xc, xob);
  k_gemm<1><<<dim3(32, 8), 256, 0, stream>>>(xob, WoT, out, nullptr, nullptr,
                                             nullptr, bo, bo, bo, 4096, 1024, 1024);
}